// Round 10
// baseline (174.846 us; speedup 1.0000x reference)
//
#include <hip/hip_runtime.h>
#include <hip/hip_bf16.h>

#define S_LEN 2048
#define EMB 1024
#define NH 16
#define HD 64
// M = B*S = 4096 rows

typedef __attribute__((ext_vector_type(8))) __bf16 bf16x8;
typedef __attribute__((ext_vector_type(4))) float f32x4;
typedef __attribute__((ext_vector_type(16))) float f32x16;
typedef __attribute__((ext_vector_type(4))) unsigned int u32x4;

__device__ inline void gload_lds16(const void* g, void* l) {
    __builtin_amdgcn_global_load_lds(
        (const __attribute__((address_space(1))) unsigned int*)g,
        (__attribute__((address_space(3))) unsigned int*)l, 16, 0, 0);
}

// ---------------------------------------------------------------------------
// Kernel 0: fp32 -> bf16 conversion of x, qkv_w, out_w in ONE launch.
// ---------------------------------------------------------------------------
__global__ __launch_bounds__(256) void cvt_all(
    const float* __restrict__ x, const float* __restrict__ wq,
    const float* __restrict__ wo,
    __hip_bfloat16* __restrict__ xb, __hip_bfloat16* __restrict__ wqb,
    __hip_bfloat16* __restrict__ wob)
{
    const long C_X = (long)4096 * 1024 / 4;       // 1,048,576
    const long C_WQ = (long)3072 * 1024 / 4;      // 786,432
    long c = (long)blockIdx.x * 256 + threadIdx.x;
    const float* in;
    __hip_bfloat16* out;
    if (c < C_X) { in = x; out = xb; }
    else if (c < C_X + C_WQ) { in = wq; out = wqb; c -= C_X; }
    else { in = wo; out = wob; c -= C_X + C_WQ; }
    long i = c * 4;
    float4 v = *(const float4*)(in + i);
    __hip_bfloat16 b0 = __float2bfloat16(v.x);
    __hip_bfloat16 b1 = __float2bfloat16(v.y);
    __hip_bfloat16 b2 = __float2bfloat16(v.z);
    __hip_bfloat16 b3 = __float2bfloat16(v.w);
    ushort4 o = {*(unsigned short*)&b0, *(unsigned short*)&b1,
                 *(unsigned short*)&b2, *(unsigned short*)&b3};
    *(ushort4*)(out + i) = o;
}

// ---------------------------------------------------------------------------
// MFMA GEMM core (m97 structure): C = A @ B^T, 128x128 tile, BK=64, 4 waves.
// EPI=0: quantum epilogue (cos*cos, scatter Q/K/Vt).  EPI=1: fp32 C store.
// Q is pre-scaled by 0.125*log2(e) so attention can use exp2 directly.
// ---------------------------------------------------------------------------
template <int EPI>
__global__ __launch_bounds__(256) void gemm_mfma(
    const __hip_bfloat16* __restrict__ A,   // [M][1024]
    const __hip_bfloat16* __restrict__ B,   // [N][1024]
    const float* __restrict__ qp,           // [64] (EPI=0)
    __hip_bfloat16* __restrict__ Q,         // EPI=0 outputs
    __hip_bfloat16* __restrict__ Kp,
    __hip_bfloat16* __restrict__ Vt,
    float* __restrict__ C)                  // EPI=1 output
{
    const int Kd = 1024;
    __shared__ __align__(16) char Ash[128 * 128];
    __shared__ __align__(16) char Bsh[128 * 128];

    const int t  = threadIdx.x;
    const int w  = t >> 6;
    const int l  = t & 63;
    const int lg = l >> 4, lm = l & 15;
    const int wr = w >> 1, wc = w & 1;
    const int m0 = blockIdx.y * 128;
    const int n0 = blockIdx.x * 128;

    const int r8 = l >> 3;
    const int sb = ((l & 7) * 16) ^ (r8 << 4);
    const char* srcA = (const char*)A + ((long)(m0 + w * 32 + r8) * Kd) * 2 + sb;
    const char* srcB = (const char*)B + ((long)(n0 + w * 32 + r8) * Kd) * 2 + sb;

    f32x4 acc[4][4];
#pragma unroll
    for (int i = 0; i < 4; i++)
#pragma unroll
        for (int j = 0; j < 4; j++) acc[i][j] = (f32x4){0.f, 0.f, 0.f, 0.f};

    for (int kt = 0; kt < Kd * 2; kt += 128) {
#pragma unroll
        for (int j = 0; j < 4; j++) {
            gload_lds16(srcA + (long)j * 8 * Kd * 2 + kt, Ash + (w * 32 + j * 8) * 128);
            gload_lds16(srcB + (long)j * 8 * Kd * 2 + kt, Bsh + (w * 32 + j * 8) * 128);
        }
        __syncthreads();
#pragma unroll
        for (int kk = 0; kk < 2; kk++) {
            bf16x8 af[4], bfr[4];
            const int sw = (lm & 7) << 4;
            const int co = (kk * 64 + lg * 16);
#pragma unroll
            for (int mi = 0; mi < 4; mi++)
                af[mi] = *(const bf16x8*)(Ash + (wr * 64 + mi * 16 + lm) * 128 + (co ^ sw));
#pragma unroll
            for (int ni = 0; ni < 4; ni++)
                bfr[ni] = *(const bf16x8*)(Bsh + (wc * 64 + ni * 16 + lm) * 128 + (co ^ sw));
#pragma unroll
            for (int mi = 0; mi < 4; mi++)
#pragma unroll
                for (int ni = 0; ni < 4; ni++)
                    acc[mi][ni] = __builtin_amdgcn_mfma_f32_16x16x32_bf16(
                        af[mi], bfr[ni], acc[mi][ni], 0, 0, 0);
        }
        __syncthreads();
    }

    if constexpr (EPI == 0) {
        const int which = n0 >> 10;
        float cqp[4];
#pragma unroll
        for (int ni = 0; ni < 4; ni++)
            cqp[ni] = __cosf(qp[(wc * 64 + ni * 16 + lm) & 63]);
#pragma unroll
        for (int mi = 0; mi < 4; mi++) {
#pragma unroll
            for (int r = 0; r < 4; r++) {
                int m = m0 + wr * 64 + mi * 16 + lg * 4 + r;
                int b = m >> 11, s = m & 2047;
#pragma unroll
                for (int ni = 0; ni < 4; ni++) {
                    int n = n0 + wc * 64 + ni * 16 + lm;
                    int d = n & 63;
                    int h = (n & 1023) >> 6;
                    int bh = b * NH + h;
                    float val = __cosf(acc[mi][ni][r]) * cqp[ni];
                    if (which == 0)  // 0.125 * log2(e) folded for exp2 softmax
                        Q[((long)bh * S_LEN + s) * HD + d] = __float2bfloat16(val * 0.180336880f);
                    else if (which == 1)
                        Kp[((long)bh * S_LEN + s) * HD + d] = __float2bfloat16(val);
                    else
                        Vt[((long)bh * HD + d) * S_LEN + s] = __float2bfloat16(val);
                }
            }
        }
    } else {
#pragma unroll
        for (int mi = 0; mi < 4; mi++)
#pragma unroll
            for (int r = 0; r < 4; r++) {
                int m = m0 + wr * 64 + mi * 16 + lg * 4 + r;
#pragma unroll
                for (int ni = 0; ni < 4; ni++) {
                    int n = n0 + wc * 64 + ni * 16 + lm;
                    C[(long)m * 1024 + n] = acc[mi][ni][r];
                }
            }
    }
}

// ---------------------------------------------------------------------------
// Kernel 2: MFMA flash attention, 32x32x16, in-register P, 64 q/wave,
// split-K x4 (round-9 structure) + T3/T4 pipeline: DOUBLE-buffered K/V with
// counted-drain placement — STAGE(next->alt) at loop top, compute(cur),
// then s_waitcnt vmcnt(0) + raw s_barrier at loop END. Next tile's DMA has
// the whole compute phase to land (the round-7/9 versions drained at the
// top, right after issue — full latency exposed). One barrier per tile.
// ---------------------------------------------------------------------------
__global__ __launch_bounds__(128, 3) void attn_mfma(
    const __hip_bfloat16* __restrict__ Q,
    const __hip_bfloat16* __restrict__ K,
    const __hip_bfloat16* __restrict__ Vt,     // [B,H,D,S]
    __hip_bfloat16* __restrict__ Oacc,         // [4][BH][S][D] bf16 partials
    float* __restrict__ Lw)                    // [4][BH][S] f32 partial lsum
{
    __shared__ __align__(16) char Ksh[2][64 * 128];  // 64 keys x 64 d (swz)
    __shared__ __align__(16) char Vsh[2][64 * 128];  // 64 d x 64 keys (swz)

    const int bh = blockIdx.y;
    const int q0 = blockIdx.x * 128;
    const int z  = blockIdx.z;           // k-split 0..3
    const int t  = threadIdx.x;          // 0..127
    const int w  = t >> 6;               // wave 0..1
    const int l  = t & 63;
    const int lo5 = l & 31;
    const int hi  = l >> 5;
    const int qbase = q0 + w * 64;

    // Q fragments (pre-scaled by 0.125*log2e): g in {0,1} -> q = qbase+g*32+lo5
    bf16x8 qf[2][4];
#pragma unroll
    for (int g = 0; g < 2; g++) {
        const char* Qr =
            (const char*)(Q + ((long)bh * S_LEN + qbase + g * 32 + lo5) * HD);
#pragma unroll
        for (int ks = 0; ks < 4; ks++)
            qf[g][ks] = *(const bf16x8*)(Qr + ks * 32 + hi * 16);
    }

    f32x16 oacc[2][2] = {};
    float lsum[2] = {0.f, 0.f};
    const float EXPB = 11.54156033f;  // 8 * log2(e)

    const char* Kgb = (const char*)(K + (long)bh * S_LEN * HD);
    const char* Vgb = (const char*)(Vt + (long)bh * HD * S_LEN);

    // staging: chunk c = t + 128*j -> row (t>>3)+16j, 16B col t&7; linear LDS
    // dest (t*16 + j*2048); source byte pre-swizzled by ((row&7)<<4).
    const int swb = ((t & 7) * 16) ^ (((t >> 3) & 7) << 4);
    const int r0 = t >> 3;
    const int swr = (lo5 & 7) << 4;

#define STAGE(buf, ktv)                                                        \
    do {                                                                       \
        _Pragma("unroll") for (int j = 0; j < 4; j++)                          \
            gload_lds16(Kgb + (long)((ktv) + r0 + 16 * j) * 128 + swb,         \
                        Ksh[buf] + t * 16 + j * 2048);                         \
        _Pragma("unroll") for (int j = 0; j < 4; j++)                          \
            gload_lds16(Vgb + (long)(r0 + 16 * j) * 4096 + (long)(ktv) * 2 + swb, \
                        Vsh[buf] + t * 16 + j * 2048);                         \
    } while (0)

    // prologue: stage tile 0, drain, publish
    STAGE(0, z * 512);
    asm volatile("s_waitcnt vmcnt(0)" ::: "memory");
    __builtin_amdgcn_s_barrier();
    __builtin_amdgcn_sched_barrier(0);

    int cur = 0;
    for (int tile = 0; tile < 8; tile++) {
        // issue next tile's DMA into the alternate buffer (T14 issue-early)
        if (tile < 7) STAGE(cur ^ 1, z * 512 + (tile + 1) * 64);

        const char* Kc = Ksh[cur];
        const char* Vc = Vsh[cur];

        // ---- S^T = K Q^T + in-register softmax/P, per 32-key block ----
        bf16x8 pa[2][4];
#pragma unroll
        for (int n0 = 0; n0 < 2; n0++) {
            const char* Krow = Kc + (n0 * 32 + lo5) * 128;
            f32x16 s0 = {}, s1 = {};
            __builtin_amdgcn_s_setprio(1);
#pragma unroll
            for (int ks = 0; ks < 4; ks++) {
                bf16x8 kf = *(const bf16x8*)(Krow + ((ks * 32 + hi * 16) ^ swr));
                s0 = __builtin_amdgcn_mfma_f32_32x32x16_bf16(kf, qf[0][ks], s0, 0, 0, 0);
                s1 = __builtin_amdgcn_mfma_f32_32x32x16_bf16(kf, qf[1][ks], s1, 0, 0, 0);
            }
            __builtin_amdgcn_s_setprio(0);
#pragma unroll
            for (int g = 0; g < 2; g++) {
                const f32x16& sv = g ? s1 : s0;
                float p[16];
#pragma unroll
                for (int r = 0; r < 16; r++)
                    p[r] = __builtin_amdgcn_exp2f(sv[r] - EXPB);
#pragma unroll
                for (int r = 0; r < 16; r += 4)
                    lsum[g] += (p[r] + p[r + 1]) + (p[r + 2] + p[r + 3]);
                unsigned c0, c1, c2, c3, c4, c5, c6, c7;
                asm("v_cvt_pk_bf16_f32 %0, %1, %2" : "=v"(c0) : "v"(p[0]),  "v"(p[1]));
                asm("v_cvt_pk_bf16_f32 %0, %1, %2" : "=v"(c1) : "v"(p[2]),  "v"(p[3]));
                asm("v_cvt_pk_bf16_f32 %0, %1, %2" : "=v"(c2) : "v"(p[4]),  "v"(p[5]));
                asm("v_cvt_pk_bf16_f32 %0, %1, %2" : "=v"(c3) : "v"(p[6]),  "v"(p[7]));
                asm("v_cvt_pk_bf16_f32 %0, %1, %2" : "=v"(c4) : "v"(p[8]),  "v"(p[9]));
                asm("v_cvt_pk_bf16_f32 %0, %1, %2" : "=v"(c5) : "v"(p[10]), "v"(p[11]));
                asm("v_cvt_pk_bf16_f32 %0, %1, %2" : "=v"(c6) : "v"(p[12]), "v"(p[13]));
                asm("v_cvt_pk_bf16_f32 %0, %1, %2" : "=v"(c7) : "v"(p[14]), "v"(p[15]));
                asm("v_permlane32_swap_b32 %0, %1" : "+v"(c0), "+v"(c2));
                asm("v_permlane32_swap_b32 %0, %1" : "+v"(c1), "+v"(c3));
                asm("v_permlane32_swap_b32 %0, %1" : "+v"(c4), "+v"(c6));
                asm("v_permlane32_swap_b32 %0, %1" : "+v"(c5), "+v"(c7));
                u32x4 w0 = {c0, c1, c2, c3};
                u32x4 w1 = {c4, c5, c6, c7};
                pa[g][n0 * 2]     = __builtin_bit_cast(bf16x8, w0);
                pa[g][n0 * 2 + 1] = __builtin_bit_cast(bf16x8, w1);
            }
        }

        // ---- O += P V : vf shared across both q-fragments ----
        __builtin_amdgcn_s_setprio(1);
#pragma unroll
        for (int db = 0; db < 2; db++) {
            const char* Vrow = Vc + (db * 32 + lo5) * 128;
#pragma unroll
            for (int ks = 0; ks < 4; ks++) {
                bf16x8 vf = *(const bf16x8*)(Vrow + ((ks * 32 + hi * 16) ^ swr));
                oacc[0][db] = __builtin_amdgcn_mfma_f32_32x32x16_bf16(
                    pa[0][ks], vf, oacc[0][db], 0, 0, 0);
                oacc[1][db] = __builtin_amdgcn_mfma_f32_32x32x16_bf16(
                    pa[1][ks], vf, oacc[1][db], 0, 0, 0);
            }
        }
        __builtin_amdgcn_s_setprio(0);

        // ---- end-of-tile: drain next-tile DMA (hidden by compute above),
        //      publish alt buffer, protect cur from next overwrite ----
        asm volatile("s_waitcnt vmcnt(0)" ::: "memory");
        __builtin_amdgcn_s_barrier();
        __builtin_amdgcn_sched_barrier(0);
        cur ^= 1;
    }
#undef STAGE

    // ---- partial epilogue: store bf16 O_unnorm + f32 lsum for this split ----
#pragma unroll
    for (int g = 0; g < 2; g++) {
        lsum[g] += __shfl_xor(lsum[g], 32, 64);
        if (l < 32)
            Lw[((long)z * 32 + bh) * S_LEN + qbase + g * 32 + lo5] = lsum[g];
    }
    __hip_bfloat16* Ob = Oacc + (((long)z * 32 + bh) * S_LEN) * HD;
#pragma unroll
    for (int g = 0; g < 2; g++)
#pragma unroll
        for (int db = 0; db < 2; db++)
#pragma unroll
            for (int r = 0; r < 16; r++) {
                int qr = (r & 3) + 8 * (r >> 2) + 4 * hi;
                Ob[(long)(qbase + g * 32 + qr) * HD + db * 32 + lo5] =
                    __float2bfloat16(oacc[g][db][r]);
            }
}

// ---------------------------------------------------------------------------
// Kernel 3: combine 4 split-K partials, normalize, write O [B,S,E] bf16.
// ---------------------------------------------------------------------------
__global__ __launch_bounds__(256) void attn_norm(
    const __hip_bfloat16* __restrict__ Oacc,  // [4][BH*S*D]
    const float* __restrict__ Lw,             // [4][BH*S]
    __hip_bfloat16* __restrict__ O)           // [B,S,E]
{
    const long NE = (long)32 * S_LEN * HD;    // 4,194,304
    long e = ((long)blockIdx.x * 256 + threadIdx.x) * 4;
    int row = (int)(e >> 6);                  // bh*2048 + s
    int d0 = (int)(e & 63);
    int bh = row >> 11, s = row & 2047;
    float Ls = Lw[row] + Lw[row + 65536] + Lw[row + 131072] + Lw[row + 196608];
    float inv = 1.f / Ls;
    float acc[4] = {0.f, 0.f, 0.f, 0.f};
#pragma unroll
    for (int z = 0; z < 4; z++) {
        ushort4 v = *(const ushort4*)(Oacc + z * NE + e);
        unsigned short* pv = (unsigned short*)&v;
#pragma unroll
        for (int j = 0; j < 4; j++)
            acc[j] += __bfloat162float(*(__hip_bfloat16*)&pv[j]);
    }
    int b = bh >> 4, h = bh & 15;
    ushort4 o;
    unsigned short* po = (unsigned short*)&o;
#pragma unroll
    for (int j = 0; j < 4; j++) {
        __hip_bfloat16 bv = __float2bfloat16(acc[j] * inv);
        po[j] = *(unsigned short*)&bv;
    }
    *(ushort4*)(O + ((long)(b * S_LEN + s)) * EMB + h * HD + d0) = o;
}

extern "C" void kernel_launch(void* const* d_in, const int* in_sizes, int n_in,
                              void* d_out, int out_size, void* d_ws, size_t ws_size,
                              hipStream_t stream) {
    const float* x     = (const float*)d_in[0];   // [2,2048,1024]
    const float* qkv_w = (const float*)d_in[1];   // [3072,1024]
    const float* out_w = (const float*)d_in[2];   // [1024,1024]
    const float* qp    = (const float*)d_in[3];   // [64]
    float* out = (float*)d_out;                   // [2,2048,1024] fp32

    const long NELEM = (long)2 * S_LEN * EMB;     // 4,194,304
    __hip_bfloat16* Q    = (__hip_bfloat16*)d_ws; // [B,H,S,D] (x 0.125*log2e)
    __hip_bfloat16* K    = Q + NELEM;             // [B,H,S,D]
    __hip_bfloat16* Vt   = K + NELEM;             // [B,H,D,S]
    __hip_bfloat16* O    = Vt + NELEM;            // [B,S,E]
    __hip_bfloat16* xb   = O + NELEM;             // [4096][1024]
    __hip_bfloat16* wqb  = xb + NELEM;            // [3072][1024]
    __hip_bfloat16* wob  = wqb + (long)3072 * 1024; // [1024][1024]
    __hip_bfloat16* Oacc = wob + (long)1024 * 1024; // [4][BH,S,D] bf16 = 32MB
    float*          Lw   = (float*)(Oacc + 4 * NELEM); // [4][BH,S] f32 = 1MB

    dim3 blk(256);
    cvt_all<<<dim3(8192), blk, 0, stream>>>(x, qkv_w, out_w, xb, wqb, wob);
    gemm_mfma<0><<<dim3(3072 / 128, 4096 / 128), blk, 0, stream>>>(
        xb, wqb, qp, Q, K, Vt, nullptr);
    attn_mfma<<<dim3(S_LEN / 128, 32, 4), dim3(128), 0, stream>>>(
        Q, K, Vt, Oacc, Lw);
    attn_norm<<<dim3(4096), blk, 0, stream>>>(Oacc, Lw, O);
    gemm_mfma<1><<<dim3(1024 / 128, 4096 / 128), blk, 0, stream>>>(
        O, wob, nullptr, nullptr, nullptr, nullptr, out);
}

// Round 11
// 139.714 us; speedup vs baseline: 1.2515x; 1.2515x over previous
//
#include <hip/hip_runtime.h>
#include <hip/hip_bf16.h>

#define S_LEN 2048
#define EMB 1024
#define NH 16
#define HD 64
// M = B*S = 4096 rows

typedef __attribute__((ext_vector_type(8))) __bf16 bf16x8;
typedef __attribute__((ext_vector_type(4))) float f32x4;

__device__ inline void gload_lds16(const void* g, void* l) {
    __builtin_amdgcn_global_load_lds(
        (const __attribute__((address_space(1))) unsigned int*)g,
        (__attribute__((address_space(3))) unsigned int*)l, 16, 0, 0);
}

// ---------------------------------------------------------------------------
// Kernel 0: fp32 -> bf16 conversion of x, qkv_w, out_w in ONE launch.
// ---------------------------------------------------------------------------
__global__ __launch_bounds__(256) void cvt_all(
    const float* __restrict__ x, const float* __restrict__ wq,
    const float* __restrict__ wo,
    __hip_bfloat16* __restrict__ xb, __hip_bfloat16* __restrict__ wqb,
    __hip_bfloat16* __restrict__ wob)
{
    const long C_X = (long)4096 * 1024 / 4;       // 1,048,576
    const long C_WQ = (long)3072 * 1024 / 4;      // 786,432
    long c = (long)blockIdx.x * 256 + threadIdx.x;
    const float* in;
    __hip_bfloat16* out;
    if (c < C_X) { in = x; out = xb; }
    else if (c < C_X + C_WQ) { in = wq; out = wqb; c -= C_X; }
    else { in = wo; out = wob; c -= C_X + C_WQ; }
    long i = c * 4;
    float4 v = *(const float4*)(in + i);
    __hip_bfloat16 b0 = __float2bfloat16(v.x);
    __hip_bfloat16 b1 = __float2bfloat16(v.y);
    __hip_bfloat16 b2 = __float2bfloat16(v.z);
    __hip_bfloat16 b3 = __float2bfloat16(v.w);
    ushort4 o = {*(unsigned short*)&b0, *(unsigned short*)&b1,
                 *(unsigned short*)&b2, *(unsigned short*)&b3};
    *(ushort4*)(out + i) = o;
}

// ---------------------------------------------------------------------------
// MFMA GEMM core (m97 structure): C = A @ B^T, 128x128 tile, BK=64, 4 waves.
// EPI=0: quantum epilogue (cos*cos, scatter Q/K/Vt). V goes through a
// per-wave LDS transpose (reusing Ash/Bsh after the K-loop) so the Vt
// [B,H,D,S] store is 128B-contiguous instead of a 2B/lane x 4KB-stride
// scatter. EPI=1: fp32 C store.
// Q is pre-scaled by 0.125*log2(e) so attention can use exp2 directly.
// ---------------------------------------------------------------------------
template <int EPI>
__global__ __launch_bounds__(256) void gemm_mfma(
    const __hip_bfloat16* __restrict__ A,   // [M][1024]
    const __hip_bfloat16* __restrict__ B,   // [N][1024]
    const float* __restrict__ qp,           // [64] (EPI=0)
    __hip_bfloat16* __restrict__ Q,         // EPI=0 outputs
    __hip_bfloat16* __restrict__ Kp,
    __hip_bfloat16* __restrict__ Vt,
    float* __restrict__ C)                  // EPI=1 output
{
    const int Kd = 1024;
    __shared__ __align__(16) char Ash[128 * 128];
    __shared__ __align__(16) char Bsh[128 * 128];

    const int t  = threadIdx.x;
    const int w  = t >> 6;
    const int l  = t & 63;
    const int lg = l >> 4, lm = l & 15;
    const int wr = w >> 1, wc = w & 1;
    const int m0 = blockIdx.y * 128;
    const int n0 = blockIdx.x * 128;

    const int r8 = l >> 3;
    const int sb = ((l & 7) * 16) ^ (r8 << 4);
    const char* srcA = (const char*)A + ((long)(m0 + w * 32 + r8) * Kd) * 2 + sb;
    const char* srcB = (const char*)B + ((long)(n0 + w * 32 + r8) * Kd) * 2 + sb;

    f32x4 acc[4][4];
#pragma unroll
    for (int i = 0; i < 4; i++)
#pragma unroll
        for (int j = 0; j < 4; j++) acc[i][j] = (f32x4){0.f, 0.f, 0.f, 0.f};

    for (int kt = 0; kt < Kd * 2; kt += 128) {
#pragma unroll
        for (int j = 0; j < 4; j++) {
            gload_lds16(srcA + (long)j * 8 * Kd * 2 + kt, Ash + (w * 32 + j * 8) * 128);
            gload_lds16(srcB + (long)j * 8 * Kd * 2 + kt, Bsh + (w * 32 + j * 8) * 128);
        }
        __syncthreads();
#pragma unroll
        for (int kk = 0; kk < 2; kk++) {
            bf16x8 af[4], bfr[4];
            const int sw = (lm & 7) << 4;
            const int co = (kk * 64 + lg * 16);
#pragma unroll
            for (int mi = 0; mi < 4; mi++)
                af[mi] = *(const bf16x8*)(Ash + (wr * 64 + mi * 16 + lm) * 128 + (co ^ sw));
#pragma unroll
            for (int ni = 0; ni < 4; ni++)
                bfr[ni] = *(const bf16x8*)(Bsh + (wc * 64 + ni * 16 + lm) * 128 + (co ^ sw));
#pragma unroll
            for (int mi = 0; mi < 4; mi++)
#pragma unroll
                for (int ni = 0; ni < 4; ni++)
                    acc[mi][ni] = __builtin_amdgcn_mfma_f32_16x16x32_bf16(
                        af[mi], bfr[ni], acc[mi][ni], 0, 0, 0);
        }
        __syncthreads();
    }

    if constexpr (EPI == 0) {
        const int which = n0 >> 10;
        float cqp[4];
#pragma unroll
        for (int ni = 0; ni < 4; ni++)
            cqp[ni] = __cosf(qp[(wc * 64 + ni * 16 + lm) & 63]);

        if (which == 2) {
            // ---- V: per-wave LDS transpose -> coalesced Vt[d][s] stores ----
            // Wave-private 8KB region (Ash/Bsh are dead after the K-loop;
            // last __syncthreads() already passed). Write T[d][s_local] with
            // (d&7)<<4 XOR (2-way aliasing = free), read 16B rows back.
            char* T = (w < 2 ? Ash : Bsh) + (w & 1) * 8192;
#pragma unroll
            for (int mi = 0; mi < 4; mi++)
#pragma unroll
                for (int r = 0; r < 4; r++)
#pragma unroll
                    for (int ni = 0; ni < 4; ni++) {
                        int row = ni * 16 + lm;            // d (0..63)
                        int col = mi * 16 + lg * 4 + r;    // s-local (0..63)
                        float val = __cosf(acc[mi][ni][r]) * cqp[ni];
                        *(__hip_bfloat16*)(T + row * 128 +
                                           ((col * 2) ^ ((row & 7) << 4))) =
                            __float2bfloat16(val);
                    }
            // per-wave region: no barrier needed; compiler inserts lgkmcnt
            const int h  = ((n0 & 1023) >> 6) + wc;
            const int bh = (m0 >> 11) * NH + h;
            const int sbase = (m0 & 2047) + wr * 64;
#pragma unroll
            for (int j = 0; j < 8; j++) {
                int c = j * 64 + l;
                int d = c >> 3;
                int sc = (c & 7) * 16;   // byte offset within the 128B s-run
                uint4 v = *(const uint4*)(T + d * 128 + (sc ^ ((d & 7) << 4)));
                *(uint4*)((char*)(Vt + ((long)bh * HD + d) * S_LEN + sbase) + sc) = v;
            }
        } else {
#pragma unroll
            for (int mi = 0; mi < 4; mi++) {
#pragma unroll
                for (int r = 0; r < 4; r++) {
                    int m = m0 + wr * 64 + mi * 16 + lg * 4 + r;
                    int b = m >> 11, s = m & 2047;
#pragma unroll
                    for (int ni = 0; ni < 4; ni++) {
                        int n = n0 + wc * 64 + ni * 16 + lm;
                        int d = n & 63;
                        int h = (n & 1023) >> 6;
                        int bh = b * NH + h;
                        float val = __cosf(acc[mi][ni][r]) * cqp[ni];
                        if (which == 0)  // 0.125*log2(e) folded for exp2 softmax
                            Q[((long)bh * S_LEN + s) * HD + d] =
                                __float2bfloat16(val * 0.180336880f);
                        else
                            Kp[((long)bh * S_LEN + s) * HD + d] = __float2bfloat16(val);
                    }
                }
            }
        }
    } else {
#pragma unroll
        for (int mi = 0; mi < 4; mi++)
#pragma unroll
            for (int r = 0; r < 4; r++) {
                int m = m0 + wr * 64 + mi * 16 + lg * 4 + r;
#pragma unroll
                for (int ni = 0; ni < 4; ni++) {
                    int n = n0 + wc * 64 + ni * 16 + lm;
                    C[(long)m * 1024 + n] = acc[mi][ni][r];
                }
            }
    }
}

// ---------------------------------------------------------------------------
// Kernel 2: MFMA flash attention — round-7 proven kernel (77.7us). QBLK=64,
// 4 waves, double-buffered K/V DMA staging, ONE barrier per tile (barrier ->
// issue next DMA -> compute cur). Swapped QK^T (lane-local softmax rows),
// fixed-max exp2 softmax (log2e pre-folded into Q), P packed to ds_write_b64,
// setprio around MFMA clusters.
// ---------------------------------------------------------------------------
__global__ __launch_bounds__(256) void attn_mfma(
    const __hip_bfloat16* __restrict__ Q,
    const __hip_bfloat16* __restrict__ K,
    const __hip_bfloat16* __restrict__ Vt,  // [B,H,D,S]
    __hip_bfloat16* __restrict__ O)
{
    __shared__ __align__(16) char Ksh[2][64 * 128];  // 64 keys x 64 d (swz)
    __shared__ __align__(16) char Vsh[2][64 * 128];  // 64 d x 64 keys (swz)
    __shared__ __align__(16) char Psh[4 * 2048];     // per-wave 16 q x 128B (swz)

    const int bh = blockIdx.y;
    const int b  = bh >> 4, h = bh & 15;
    const int q0 = blockIdx.x * 64;
    const int t  = threadIdx.x;
    const int w  = t >> 6;
    const int l  = t & 63;
    const int lg = l >> 4;
    const int lm = l & 15;

    // Q fragment (pre-scaled by 0.125*log2e): lane holds Q[q=w*16+lm][lg*8..]
    const __hip_bfloat16* Qr =
        Q + ((long)bh * S_LEN + q0 + w * 16 + lm) * HD + lg * 8;
    const bf16x8 qa0 = *(const bf16x8*)(Qr);
    const bf16x8 qa1 = *(const bf16x8*)(Qr + 32);

    f32x4 oacc[4];
#pragma unroll
    for (int n = 0; n < 4; n++) oacc[n] = (f32x4){0.f, 0.f, 0.f, 0.f};
    float lsum = 0.f;

    char* Pw = Psh + w * 2048;
    const int swp = (lm & 7) << 4;
    const float EXPB = 11.54156033f;  // 8 * log2(e)

    const char* Kgb = (const char*)(K + (long)bh * S_LEN * HD);
    const char* Vgb = (const char*)(Vt + (long)bh * HD * S_LEN);

    // DMA staging: lane l covers LDS row rr = w*8 + (l>>3) (+32 chunk 2),
    // 16B col (l&7). Linear LDS dest; source byte pre-swizzled by ((rr&7)<<4).
    const int swb = ((l & 7) * 16) ^ (((l >> 3) & 7) << 4);
    const int row0 = w * 8 + (l >> 3);
    const char* Ksrc  = Kgb + (long)row0 * 128 + swb;                  // +kt*128
    const char* Vsrc0 = Vgb + (long)row0 * (S_LEN * 2) + swb;          // +kt*2
    const char* Vsrc1 = Vgb + (long)(row0 + 32) * (S_LEN * 2) + swb;   // +kt*2

    // prologue: stage tile 0 into buffer 0
    gload_lds16(Ksrc, Ksh[0] + w * 1024);
    gload_lds16(Ksrc + 32 * 128, Ksh[0] + w * 1024 + 4096);
    gload_lds16(Vsrc0, Vsh[0] + w * 1024);
    gload_lds16(Vsrc1, Vsh[0] + w * 1024 + 4096);

    int cur = 0;
    for (int kt = 0; kt < S_LEN; kt += 64) {
        __syncthreads();  // vmcnt(0) drained -> buf[cur] staged; alt reads done

        if (kt + 64 < S_LEN) {  // stage next tile into alternate buffer
            int nk = kt + 64;
            gload_lds16(Ksrc + (long)nk * 128, Ksh[cur ^ 1] + w * 1024);
            gload_lds16(Ksrc + (long)(nk + 32) * 128, Ksh[cur ^ 1] + w * 1024 + 4096);
            gload_lds16(Vsrc0 + (long)nk * 2, Vsh[cur ^ 1] + w * 1024);
            gload_lds16(Vsrc1 + (long)nk * 2, Vsh[cur ^ 1] + w * 1024 + 4096);
        }

        const char* Kc = Ksh[cur];
        const char* Vc = Vsh[cur];

        // ---- S^T = K Q^T (A-frag = K row, B-frag = Q row; q = lm lane-local)
        f32x4 sacc[4];
        __builtin_amdgcn_s_setprio(1);
#pragma unroll
        for (int n0 = 0; n0 < 4; n0++) {
            int row = n0 * 16 + lm;
            int swr = (row & 7) << 4;
            bf16x8 k0 = *(const bf16x8*)(Kc + row * 128 + ((lg * 16) ^ swr));
            bf16x8 k1 = *(const bf16x8*)(Kc + row * 128 + ((64 + lg * 16) ^ swr));
            f32x4 s = (f32x4){0.f, 0.f, 0.f, 0.f};
            s = __builtin_amdgcn_mfma_f32_16x16x32_bf16(k0, qa0, s, 0, 0, 0);
            s = __builtin_amdgcn_mfma_f32_16x16x32_bf16(k1, qa1, s, 0, 0, 0);
            sacc[n0] = s;  // S[q=lm][key = kt + n0*16 + lg*4 + r]
        }
        __builtin_amdgcn_s_setprio(0);

        // ---- fixed-max softmax, lane-local row q=lm; pack 4 bf16 -> b64 ----
#pragma unroll
        for (int n0 = 0; n0 < 4; n0++) {
            float p0 = exp2f(sacc[n0][0] - EXPB);
            float p1 = exp2f(sacc[n0][1] - EXPB);
            float p2 = exp2f(sacc[n0][2] - EXPB);
            float p3 = exp2f(sacc[n0][3] - EXPB);
            lsum += (p0 + p1) + (p2 + p3);
            __hip_bfloat16 h0 = __float2bfloat16(p0), h1 = __float2bfloat16(p1);
            __hip_bfloat16 h2 = __float2bfloat16(p2), h3 = __float2bfloat16(p3);
            uint2 pw;
            pw.x = (unsigned)*(unsigned short*)&h0 |
                   ((unsigned)*(unsigned short*)&h1 << 16);
            pw.y = (unsigned)*(unsigned short*)&h2 |
                   ((unsigned)*(unsigned short*)&h3 << 16);
            int kb = (n0 * 16 + lg * 4) * 2;     // multiple of 8 -> b64 aligned
            *(uint2*)(Pw + lm * 128 + (kb ^ swp)) = pw;
        }

        // ---- O += P V  (A = P from per-wave LDS, B = V^T swizzled tile) ----
        __builtin_amdgcn_s_setprio(1);
#pragma unroll
        for (int kk = 0; kk < 2; kk++) {
            bf16x8 pa = *(const bf16x8*)(Pw + lm * 128 + ((kk * 64 + lg * 16) ^ swp));
#pragma unroll
            for (int n0 = 0; n0 < 4; n0++) {
                int row = n0 * 16 + lm;  // d index
                bf16x8 vb = *(const bf16x8*)(
                    Vc + row * 128 + ((kk * 64 + lg * 16) ^ ((row & 7) << 4)));
                oacc[n0] = __builtin_amdgcn_mfma_f32_16x16x32_bf16(
                    pa, vb, oacc[n0], 0, 0, 0);
            }
        }
        __builtin_amdgcn_s_setprio(0);
        cur ^= 1;
    }

    // lsum: lane holds partial for q=lm over its 16 keys/tile; sum over lg
    lsum += __shfl_xor(lsum, 16, 64);
    lsum += __shfl_xor(lsum, 32, 64);
    // oacc rows are q = lg*4 + r; totals live at lane lm == q
#pragma unroll
    for (int r = 0; r < 4; r++) {
        float inv = 1.f / __shfl(lsum, lg * 4 + r, 64);
        int qrow = q0 + w * 16 + lg * 4 + r;
        long base = ((long)b * S_LEN + qrow) * EMB + h * HD;
#pragma unroll
        for (int n0 = 0; n0 < 4; n0++)
            O[base + n0 * 16 + lm] = __float2bfloat16(oacc[n0][r] * inv);
    }
}

extern "C" void kernel_launch(void* const* d_in, const int* in_sizes, int n_in,
                              void* d_out, int out_size, void* d_ws, size_t ws_size,
                              hipStream_t stream) {
    const float* x     = (const float*)d_in[0];   // [2,2048,1024]
    const float* qkv_w = (const float*)d_in[1];   // [3072,1024]
    const float* out_w = (const float*)d_in[2];   // [1024,1024]
    const float* qp    = (const float*)d_in[3];   // [64]
    float* out = (float*)d_out;                   // [2,2048,1024] fp32

    const long NELEM = (long)2 * S_LEN * EMB;     // 4,194,304
    __hip_bfloat16* Q   = (__hip_bfloat16*)d_ws;  // [B,H,S,D] (x 0.125*log2e)
    __hip_bfloat16* K   = Q + NELEM;              // [B,H,S,D]
    __hip_bfloat16* Vt  = K + NELEM;              // [B,H,D,S]
    __hip_bfloat16* O   = Vt + NELEM;             // [B,S,E]
    __hip_bfloat16* xb  = O + NELEM;              // [4096][1024]
    __hip_bfloat16* wqb = xb + NELEM;             // [3072][1024]
    __hip_bfloat16* wob = wqb + (long)3072 * 1024;// [1024][1024]

    dim3 blk(256);
    cvt_all<<<dim3(8192), blk, 0, stream>>>(x, qkv_w, out_w, xb, wqb, wob);
    gemm_mfma<0><<<dim3(3072 / 128, 4096 / 128), blk, 0, stream>>>(
        xb, wqb, qp, Q, K, Vt, nullptr);
    attn_mfma<<<dim3(S_LEN / 64, 32), blk, 0, stream>>>(Q, K, Vt, O);
    gemm_mfma<1><<<dim3(1024 / 128, 4096 / 128), blk, 0, stream>>>(
        O, wob, nullptr, nullptr, nullptr, nullptr, out);
}

// Round 12
// 127.301 us; speedup vs baseline: 1.3735x; 1.0975x over previous
//
#include <hip/hip_runtime.h>
#include <hip/hip_bf16.h>

#define S_LEN 2048
#define EMB 1024
#define NH 16
#define HD 64
// M = B*S = 4096 rows

typedef __attribute__((ext_vector_type(8))) __bf16 bf16x8;
typedef __attribute__((ext_vector_type(4))) float f32x4;

__device__ inline void gload_lds16(const void* g, void* l) {
    __builtin_amdgcn_global_load_lds(
        (const __attribute__((address_space(1))) unsigned int*)g,
        (__attribute__((address_space(3))) unsigned int*)l, 16, 0, 0);
}

// ---------------------------------------------------------------------------
// Kernel 0: fp32 -> bf16 conversion of x, qkv_w, out_w in ONE launch.
// ---------------------------------------------------------------------------
__global__ __launch_bounds__(256) void cvt_all(
    const float* __restrict__ x, const float* __restrict__ wq,
    const float* __restrict__ wo,
    __hip_bfloat16* __restrict__ xb, __hip_bfloat16* __restrict__ wqb,
    __hip_bfloat16* __restrict__ wob)
{
    const long C_X = (long)4096 * 1024 / 4;       // 1,048,576
    const long C_WQ = (long)3072 * 1024 / 4;      // 786,432
    long c = (long)blockIdx.x * 256 + threadIdx.x;
    const float* in;
    __hip_bfloat16* out;
    if (c < C_X) { in = x; out = xb; }
    else if (c < C_X + C_WQ) { in = wq; out = wqb; c -= C_X; }
    else { in = wo; out = wob; c -= C_X + C_WQ; }
    long i = c * 4;
    float4 v = *(const float4*)(in + i);
    __hip_bfloat16 b0 = __float2bfloat16(v.x);
    __hip_bfloat16 b1 = __float2bfloat16(v.y);
    __hip_bfloat16 b2 = __float2bfloat16(v.z);
    __hip_bfloat16 b3 = __float2bfloat16(v.w);
    ushort4 o = {*(unsigned short*)&b0, *(unsigned short*)&b1,
                 *(unsigned short*)&b2, *(unsigned short*)&b3};
    *(ushort4*)(out + i) = o;
}

// ---------------------------------------------------------------------------
// MFMA GEMM core (m97 structure): C = A @ B^T, 128x128 tile, BK=64, 4 waves.
// EPI=0: quantum epilogue (cos*cos, scatter Q/K/Vt; V via per-wave LDS
// transpose for coalesced Vt stores).  EPI=1: fp32 C store.
// Q is pre-scaled by 0.125*log2(e) so attention can use exp2 directly.
// ---------------------------------------------------------------------------
template <int EPI>
__global__ __launch_bounds__(256) void gemm_mfma(
    const __hip_bfloat16* __restrict__ A,   // [M][1024]
    const __hip_bfloat16* __restrict__ B,   // [N][1024]
    const float* __restrict__ qp,           // [64] (EPI=0)
    __hip_bfloat16* __restrict__ Q,         // EPI=0 outputs
    __hip_bfloat16* __restrict__ Kp,
    __hip_bfloat16* __restrict__ Vt,
    float* __restrict__ C)                  // EPI=1 output
{
    const int Kd = 1024;
    __shared__ __align__(16) char Ash[128 * 128];
    __shared__ __align__(16) char Bsh[128 * 128];

    const int t  = threadIdx.x;
    const int w  = t >> 6;
    const int l  = t & 63;
    const int lg = l >> 4, lm = l & 15;
    const int wr = w >> 1, wc = w & 1;
    const int m0 = blockIdx.y * 128;
    const int n0 = blockIdx.x * 128;

    const int r8 = l >> 3;
    const int sb = ((l & 7) * 16) ^ (r8 << 4);
    const char* srcA = (const char*)A + ((long)(m0 + w * 32 + r8) * Kd) * 2 + sb;
    const char* srcB = (const char*)B + ((long)(n0 + w * 32 + r8) * Kd) * 2 + sb;

    f32x4 acc[4][4];
#pragma unroll
    for (int i = 0; i < 4; i++)
#pragma unroll
        for (int j = 0; j < 4; j++) acc[i][j] = (f32x4){0.f, 0.f, 0.f, 0.f};

    for (int kt = 0; kt < Kd * 2; kt += 128) {
#pragma unroll
        for (int j = 0; j < 4; j++) {
            gload_lds16(srcA + (long)j * 8 * Kd * 2 + kt, Ash + (w * 32 + j * 8) * 128);
            gload_lds16(srcB + (long)j * 8 * Kd * 2 + kt, Bsh + (w * 32 + j * 8) * 128);
        }
        __syncthreads();
#pragma unroll
        for (int kk = 0; kk < 2; kk++) {
            bf16x8 af[4], bfr[4];
            const int sw = (lm & 7) << 4;
            const int co = (kk * 64 + lg * 16);
#pragma unroll
            for (int mi = 0; mi < 4; mi++)
                af[mi] = *(const bf16x8*)(Ash + (wr * 64 + mi * 16 + lm) * 128 + (co ^ sw));
#pragma unroll
            for (int ni = 0; ni < 4; ni++)
                bfr[ni] = *(const bf16x8*)(Bsh + (wc * 64 + ni * 16 + lm) * 128 + (co ^ sw));
#pragma unroll
            for (int mi = 0; mi < 4; mi++)
#pragma unroll
                for (int ni = 0; ni < 4; ni++)
                    acc[mi][ni] = __builtin_amdgcn_mfma_f32_16x16x32_bf16(
                        af[mi], bfr[ni], acc[mi][ni], 0, 0, 0);
        }
        __syncthreads();
    }

    if constexpr (EPI == 0) {
        const int which = n0 >> 10;
        float cqp[4];
#pragma unroll
        for (int ni = 0; ni < 4; ni++)
            cqp[ni] = __cosf(qp[(wc * 64 + ni * 16 + lm) & 63]);

        if (which == 2) {
            // ---- V: per-wave LDS transpose -> coalesced Vt[d][s] stores ----
            char* T = (w < 2 ? Ash : Bsh) + (w & 1) * 8192;
#pragma unroll
            for (int mi = 0; mi < 4; mi++)
#pragma unroll
                for (int r = 0; r < 4; r++)
#pragma unroll
                    for (int ni = 0; ni < 4; ni++) {
                        int row = ni * 16 + lm;            // d (0..63)
                        int col = mi * 16 + lg * 4 + r;    // s-local (0..63)
                        float val = __cosf(acc[mi][ni][r]) * cqp[ni];
                        *(__hip_bfloat16*)(T + row * 128 +
                                           ((col * 2) ^ ((row & 7) << 4))) =
                            __float2bfloat16(val);
                    }
            const int h  = ((n0 & 1023) >> 6) + wc;
            const int bh = (m0 >> 11) * NH + h;
            const int sbase = (m0 & 2047) + wr * 64;
#pragma unroll
            for (int j = 0; j < 8; j++) {
                int c = j * 64 + l;
                int d = c >> 3;
                int sc = (c & 7) * 16;
                uint4 v = *(const uint4*)(T + d * 128 + (sc ^ ((d & 7) << 4)));
                *(uint4*)((char*)(Vt + ((long)bh * HD + d) * S_LEN + sbase) + sc) = v;
            }
        } else {
#pragma unroll
            for (int mi = 0; mi < 4; mi++) {
#pragma unroll
                for (int r = 0; r < 4; r++) {
                    int m = m0 + wr * 64 + mi * 16 + lg * 4 + r;
                    int b = m >> 11, s = m & 2047;
#pragma unroll
                    for (int ni = 0; ni < 4; ni++) {
                        int n = n0 + wc * 64 + ni * 16 + lm;
                        int d = n & 63;
                        int h = (n & 1023) >> 6;
                        int bh = b * NH + h;
                        float val = __cosf(acc[mi][ni][r]) * cqp[ni];
                        if (which == 0)  // 0.125*log2(e) folded for exp2 softmax
                            Q[((long)bh * S_LEN + s) * HD + d] =
                                __float2bfloat16(val * 0.180336880f);
                        else
                            Kp[((long)bh * S_LEN + s) * HD + d] = __float2bfloat16(val);
                    }
                }
            }
        }
    } else {
#pragma unroll
        for (int mi = 0; mi < 4; mi++)
#pragma unroll
            for (int r = 0; r < 4; r++) {
                int m = m0 + wr * 64 + mi * 16 + lg * 4 + r;
#pragma unroll
                for (int ni = 0; ni < 4; ni++) {
                    int n = n0 + wc * 64 + ni * 16 + lm;
                    C[(long)m * 1024 + n] = acc[mi][ni][r];
                }
            }
    }
}

// ---------------------------------------------------------------------------
// Kernel 2: MFMA flash attention — round-7/11 proven structure (QBLK=64,
// 4 waves, double-buffered K/V DMA, one barrier/tile) with three deltas:
//  (a) XCD-aware swizzle (T1): 1-D grid, bh = (L&7) + (L>>8)*8 -> each XCD
//      owns 4 heads; their 2MB K/V fits its private L2 (FETCH 70->~35MB).
//  (b) exp2f -> __builtin_amdgcn_exp2f (raw v_exp_f32; r8/r9-validated).
//  (c) scalar bf16 cvt + OR-pack -> v_cvt_pk_bf16_f32 (2 per n0; single-op
//      pair converts, layout = adjacent keys, r8/r9-validated numerics).
// ---------------------------------------------------------------------------
__global__ __launch_bounds__(256) void attn_mfma(
    const __hip_bfloat16* __restrict__ Q,
    const __hip_bfloat16* __restrict__ K,
    const __hip_bfloat16* __restrict__ Vt,  // [B,H,D,S]
    __hip_bfloat16* __restrict__ O)
{
    __shared__ __align__(16) char Ksh[2][64 * 128];  // 64 keys x 64 d (swz)
    __shared__ __align__(16) char Vsh[2][64 * 128];  // 64 d x 64 keys (swz)
    __shared__ __align__(16) char Psh[4 * 2048];     // per-wave 16 q x 128B (swz)

    // XCD swizzle: consecutive launched blocks round-robin XCDs (L%8);
    // give XCD x the heads bh === x (mod 8) so its L2 caches only 4 heads.
    const int L  = blockIdx.x;           // 0..1023
    const int bh = (L & 7) + (L >> 8) * 8;   // (L>>8) in 0..3 -> bh 0..31
    const int q0 = ((L >> 3) & 31) * 64;
    const int b  = bh >> 4, h = bh & 15;
    const int t  = threadIdx.x;
    const int w  = t >> 6;
    const int l  = t & 63;
    const int lg = l >> 4;
    const int lm = l & 15;

    // Q fragment (pre-scaled by 0.125*log2e): lane holds Q[q=w*16+lm][lg*8..]
    const __hip_bfloat16* Qr =
        Q + ((long)bh * S_LEN + q0 + w * 16 + lm) * HD + lg * 8;
    const bf16x8 qa0 = *(const bf16x8*)(Qr);
    const bf16x8 qa1 = *(const bf16x8*)(Qr + 32);

    f32x4 oacc[4];
#pragma unroll
    for (int n = 0; n < 4; n++) oacc[n] = (f32x4){0.f, 0.f, 0.f, 0.f};
    float lsum = 0.f;

    char* Pw = Psh + w * 2048;
    const int swp = (lm & 7) << 4;
    const float EXPB = 11.54156033f;  // 8 * log2(e)

    const char* Kgb = (const char*)(K + (long)bh * S_LEN * HD);
    const char* Vgb = (const char*)(Vt + (long)bh * HD * S_LEN);

    const int swb = ((l & 7) * 16) ^ (((l >> 3) & 7) << 4);
    const int row0 = w * 8 + (l >> 3);
    const char* Ksrc  = Kgb + (long)row0 * 128 + swb;                  // +kt*128
    const char* Vsrc0 = Vgb + (long)row0 * (S_LEN * 2) + swb;          // +kt*2
    const char* Vsrc1 = Vgb + (long)(row0 + 32) * (S_LEN * 2) + swb;   // +kt*2

    // prologue: stage tile 0 into buffer 0
    gload_lds16(Ksrc, Ksh[0] + w * 1024);
    gload_lds16(Ksrc + 32 * 128, Ksh[0] + w * 1024 + 4096);
    gload_lds16(Vsrc0, Vsh[0] + w * 1024);
    gload_lds16(Vsrc1, Vsh[0] + w * 1024 + 4096);

    int cur = 0;
    for (int kt = 0; kt < S_LEN; kt += 64) {
        __syncthreads();  // vmcnt(0) drained -> buf[cur] staged; alt reads done

        if (kt + 64 < S_LEN) {  // stage next tile into alternate buffer
            int nk = kt + 64;
            gload_lds16(Ksrc + (long)nk * 128, Ksh[cur ^ 1] + w * 1024);
            gload_lds16(Ksrc + (long)(nk + 32) * 128, Ksh[cur ^ 1] + w * 1024 + 4096);
            gload_lds16(Vsrc0 + (long)nk * 2, Vsh[cur ^ 1] + w * 1024);
            gload_lds16(Vsrc1 + (long)nk * 2, Vsh[cur ^ 1] + w * 1024 + 4096);
        }

        const char* Kc = Ksh[cur];
        const char* Vc = Vsh[cur];

        // ---- S^T = K Q^T (A-frag = K row, B-frag = Q row; q = lm lane-local)
        f32x4 sacc[4];
        __builtin_amdgcn_s_setprio(1);
#pragma unroll
        for (int n0 = 0; n0 < 4; n0++) {
            int row = n0 * 16 + lm;
            int swr = (row & 7) << 4;
            bf16x8 k0 = *(const bf16x8*)(Kc + row * 128 + ((lg * 16) ^ swr));
            bf16x8 k1 = *(const bf16x8*)(Kc + row * 128 + ((64 + lg * 16) ^ swr));
            f32x4 s = (f32x4){0.f, 0.f, 0.f, 0.f};
            s = __builtin_amdgcn_mfma_f32_16x16x32_bf16(k0, qa0, s, 0, 0, 0);
            s = __builtin_amdgcn_mfma_f32_16x16x32_bf16(k1, qa1, s, 0, 0, 0);
            sacc[n0] = s;  // S[q=lm][key = kt + n0*16 + lg*4 + r]
        }
        __builtin_amdgcn_s_setprio(0);

        // ---- fixed-max softmax: raw exp2 + cvt_pk pair-converts ----
#pragma unroll
        for (int n0 = 0; n0 < 4; n0++) {
            float p0 = __builtin_amdgcn_exp2f(sacc[n0][0] - EXPB);
            float p1 = __builtin_amdgcn_exp2f(sacc[n0][1] - EXPB);
            float p2 = __builtin_amdgcn_exp2f(sacc[n0][2] - EXPB);
            float p3 = __builtin_amdgcn_exp2f(sacc[n0][3] - EXPB);
            lsum += (p0 + p1) + (p2 + p3);
            uint2 pw;
            asm("v_cvt_pk_bf16_f32 %0, %1, %2" : "=v"(pw.x) : "v"(p0), "v"(p1));
            asm("v_cvt_pk_bf16_f32 %0, %1, %2" : "=v"(pw.y) : "v"(p2), "v"(p3));
            int kb = (n0 * 16 + lg * 4) * 2;     // multiple of 8 -> b64 aligned
            *(uint2*)(Pw + lm * 128 + (kb ^ swp)) = pw;
        }

        // ---- O += P V  (A = P from per-wave LDS, B = V^T swizzled tile) ----
        __builtin_amdgcn_s_setprio(1);
#pragma unroll
        for (int kk = 0; kk < 2; kk++) {
            bf16x8 pa = *(const bf16x8*)(Pw + lm * 128 + ((kk * 64 + lg * 16) ^ swp));
#pragma unroll
            for (int n0 = 0; n0 < 4; n0++) {
                int row = n0 * 16 + lm;  // d index
                bf16x8 vb = *(const bf16x8*)(
                    Vc + row * 128 + ((kk * 64 + lg * 16) ^ ((row & 7) << 4)));
                oacc[n0] = __builtin_amdgcn_mfma_f32_16x16x32_bf16(
                    pa, vb, oacc[n0], 0, 0, 0);
            }
        }
        __builtin_amdgcn_s_setprio(0);
        cur ^= 1;
    }

    // lsum: lane holds partial for q=lm over its 16 keys/tile; sum over lg
    lsum += __shfl_xor(lsum, 16, 64);
    lsum += __shfl_xor(lsum, 32, 64);
    // oacc rows are q = lg*4 + r; totals live at lane lm == q
#pragma unroll
    for (int r = 0; r < 4; r++) {
        float inv = 1.f / __shfl(lsum, lg * 4 + r, 64);
        int qrow = q0 + w * 16 + lg * 4 + r;
        long base = ((long)b * S_LEN + qrow) * EMB + h * HD;
#pragma unroll
        for (int n0 = 0; n0 < 4; n0++)
            O[base + n0 * 16 + lm] = __float2bfloat16(oacc[n0][r] * inv);
    }
}

extern "C" void kernel_launch(void* const* d_in, const int* in_sizes, int n_in,
                              void* d_out, int out_size, void* d_ws, size_t ws_size,
                              hipStream_t stream) {
    const float* x     = (const float*)d_in[0];   // [2,2048,1024]
    const float* qkv_w = (const float*)d_in[1];   // [3072,1024]
    const float* out_w = (const float*)d_in[2];   // [1024,1024]
    const float* qp    = (const float*)d_in[3];   // [64]
    float* out = (float*)d_out;                   // [2,2048,1024] fp32

    const long NELEM = (long)2 * S_LEN * EMB;     // 4,194,304
    __hip_bfloat16* Q   = (__hip_bfloat16*)d_ws;  // [B,H,S,D] (x 0.125*log2e)
    __hip_bfloat16* K   = Q + NELEM;              // [B,H,S,D]
    __hip_bfloat16* Vt  = K + NELEM;              // [B,H,D,S]
    __hip_bfloat16* O   = Vt + NELEM;             // [B,S,E]
    __hip_bfloat16* xb  = O + NELEM;              // [4096][1024]
    __hip_bfloat16* wqb = xb + NELEM;             // [3072][1024]
    __hip_bfloat16* wob = wqb + (long)3072 * 1024;// [1024][1024]

    dim3 blk(256);
    cvt_all<<<dim3(8192), blk, 0, stream>>>(x, qkv_w, out_w, xb, wqb, wob);
    gemm_mfma<0><<<dim3(3072 / 128, 4096 / 128), blk, 0, stream>>>(
        xb, wqb, qp, Q, K, Vt, nullptr);
    attn_mfma<<<dim3(1024), blk, 0, stream>>>(Q, K, Vt, O);
    gemm_mfma<1><<<dim3(1024 / 128, 4096 / 128), blk, 0, stream>>>(
        O, wob, nullptr, nullptr, nullptr, nullptr, out);
}

// Round 13
// 118.033 us; speedup vs baseline: 1.4813x; 1.0785x over previous
//
#include <hip/hip_runtime.h>
#include <hip/hip_bf16.h>

#define S_LEN 2048
#define EMB 1024
#define NH 16
#define HD 64
// M = B*S = 4096 rows

typedef __attribute__((ext_vector_type(8))) __bf16 bf16x8;
typedef __attribute__((ext_vector_type(4))) float f32x4;
typedef __attribute__((ext_vector_type(16))) float f32x16;
typedef __attribute__((ext_vector_type(4))) unsigned int u32x4;

__device__ inline void gload_lds16(const void* g, void* l) {
    __builtin_amdgcn_global_load_lds(
        (const __attribute__((address_space(1))) unsigned int*)g,
        (__attribute__((address_space(3))) unsigned int*)l, 16, 0, 0);
}

// ---------------------------------------------------------------------------
// Kernel 0: fp32 -> bf16 conversion of x, qkv_w, out_w in ONE launch.
// ---------------------------------------------------------------------------
__global__ __launch_bounds__(256) void cvt_all(
    const float* __restrict__ x, const float* __restrict__ wq,
    const float* __restrict__ wo,
    __hip_bfloat16* __restrict__ xb, __hip_bfloat16* __restrict__ wqb,
    __hip_bfloat16* __restrict__ wob)
{
    const long C_X = (long)4096 * 1024 / 4;       // 1,048,576
    const long C_WQ = (long)3072 * 1024 / 4;      // 786,432
    long c = (long)blockIdx.x * 256 + threadIdx.x;
    const float* in;
    __hip_bfloat16* out;
    if (c < C_X) { in = x; out = xb; }
    else if (c < C_X + C_WQ) { in = wq; out = wqb; c -= C_X; }
    else { in = wo; out = wob; c -= C_X + C_WQ; }
    long i = c * 4;
    float4 v = *(const float4*)(in + i);
    __hip_bfloat16 b0 = __float2bfloat16(v.x);
    __hip_bfloat16 b1 = __float2bfloat16(v.y);
    __hip_bfloat16 b2 = __float2bfloat16(v.z);
    __hip_bfloat16 b3 = __float2bfloat16(v.w);
    ushort4 o = {*(unsigned short*)&b0, *(unsigned short*)&b1,
                 *(unsigned short*)&b2, *(unsigned short*)&b3};
    *(ushort4*)(out + i) = o;
}

// ---------------------------------------------------------------------------
// MFMA GEMM core (m97 structure): C = A @ B^T, 128x128 tile, BK=64, 4 waves.
// EPI=0: quantum epilogue (cos*cos, scatter Q/K/Vt; V via per-wave LDS
// transpose for coalesced Vt stores).  EPI=1: fp32 C store.
// Q is pre-scaled by 0.125*log2(e) so attention can use exp2 directly.
// ---------------------------------------------------------------------------
template <int EPI>
__global__ __launch_bounds__(256) void gemm_mfma(
    const __hip_bfloat16* __restrict__ A,   // [M][1024]
    const __hip_bfloat16* __restrict__ B,   // [N][1024]
    const float* __restrict__ qp,           // [64] (EPI=0)
    __hip_bfloat16* __restrict__ Q,         // EPI=0 outputs
    __hip_bfloat16* __restrict__ Kp,
    __hip_bfloat16* __restrict__ Vt,
    float* __restrict__ C)                  // EPI=1 output
{
    const int Kd = 1024;
    __shared__ __align__(16) char Ash[128 * 128];
    __shared__ __align__(16) char Bsh[128 * 128];

    const int t  = threadIdx.x;
    const int w  = t >> 6;
    const int l  = t & 63;
    const int lg = l >> 4, lm = l & 15;
    const int wr = w >> 1, wc = w & 1;
    const int m0 = blockIdx.y * 128;
    const int n0 = blockIdx.x * 128;

    const int r8 = l >> 3;
    const int sb = ((l & 7) * 16) ^ (r8 << 4);
    const char* srcA = (const char*)A + ((long)(m0 + w * 32 + r8) * Kd) * 2 + sb;
    const char* srcB = (const char*)B + ((long)(n0 + w * 32 + r8) * Kd) * 2 + sb;

    f32x4 acc[4][4];
#pragma unroll
    for (int i = 0; i < 4; i++)
#pragma unroll
        for (int j = 0; j < 4; j++) acc[i][j] = (f32x4){0.f, 0.f, 0.f, 0.f};

    for (int kt = 0; kt < Kd * 2; kt += 128) {
#pragma unroll
        for (int j = 0; j < 4; j++) {
            gload_lds16(srcA + (long)j * 8 * Kd * 2 + kt, Ash + (w * 32 + j * 8) * 128);
            gload_lds16(srcB + (long)j * 8 * Kd * 2 + kt, Bsh + (w * 32 + j * 8) * 128);
        }
        __syncthreads();
#pragma unroll
        for (int kk = 0; kk < 2; kk++) {
            bf16x8 af[4], bfr[4];
            const int sw = (lm & 7) << 4;
            const int co = (kk * 64 + lg * 16);
#pragma unroll
            for (int mi = 0; mi < 4; mi++)
                af[mi] = *(const bf16x8*)(Ash + (wr * 64 + mi * 16 + lm) * 128 + (co ^ sw));
#pragma unroll
            for (int ni = 0; ni < 4; ni++)
                bfr[ni] = *(const bf16x8*)(Bsh + (wc * 64 + ni * 16 + lm) * 128 + (co ^ sw));
#pragma unroll
            for (int mi = 0; mi < 4; mi++)
#pragma unroll
                for (int ni = 0; ni < 4; ni++)
                    acc[mi][ni] = __builtin_amdgcn_mfma_f32_16x16x32_bf16(
                        af[mi], bfr[ni], acc[mi][ni], 0, 0, 0);
        }
        __syncthreads();
    }

    if constexpr (EPI == 0) {
        const int which = n0 >> 10;
        float cqp[4];
#pragma unroll
        for (int ni = 0; ni < 4; ni++)
            cqp[ni] = __cosf(qp[(wc * 64 + ni * 16 + lm) & 63]);

        if (which == 2) {
            // ---- V: per-wave LDS transpose -> coalesced Vt[d][s] stores ----
            char* T = (w < 2 ? Ash : Bsh) + (w & 1) * 8192;
#pragma unroll
            for (int mi = 0; mi < 4; mi++)
#pragma unroll
                for (int r = 0; r < 4; r++)
#pragma unroll
                    for (int ni = 0; ni < 4; ni++) {
                        int row = ni * 16 + lm;            // d (0..63)
                        int col = mi * 16 + lg * 4 + r;    // s-local (0..63)
                        float val = __cosf(acc[mi][ni][r]) * cqp[ni];
                        *(__hip_bfloat16*)(T + row * 128 +
                                           ((col * 2) ^ ((row & 7) << 4))) =
                            __float2bfloat16(val);
                    }
            const int h  = ((n0 & 1023) >> 6) + wc;
            const int bh = (m0 >> 11) * NH + h;
            const int sbase = (m0 & 2047) + wr * 64;
#pragma unroll
            for (int j = 0; j < 8; j++) {
                int c = j * 64 + l;
                int d = c >> 3;
                int sc = (c & 7) * 16;
                uint4 v = *(const uint4*)(T + d * 128 + (sc ^ ((d & 7) << 4)));
                *(uint4*)((char*)(Vt + ((long)bh * HD + d) * S_LEN + sbase) + sc) = v;
            }
        } else {
#pragma unroll
            for (int mi = 0; mi < 4; mi++) {
#pragma unroll
                for (int r = 0; r < 4; r++) {
                    int m = m0 + wr * 64 + mi * 16 + lg * 4 + r;
                    int b = m >> 11, s = m & 2047;
#pragma unroll
                    for (int ni = 0; ni < 4; ni++) {
                        int n = n0 + wc * 64 + ni * 16 + lm;
                        int d = n & 63;
                        int h = (n & 1023) >> 6;
                        int bh = b * NH + h;
                        float val = __cosf(acc[mi][ni][r]) * cqp[ni];
                        if (which == 0)  // 0.125*log2(e) folded for exp2 softmax
                            Q[((long)bh * S_LEN + s) * HD + d] =
                                __float2bfloat16(val * 0.180336880f);
                        else
                            Kp[((long)bh * S_LEN + s) * HD + d] = __float2bfloat16(val);
                    }
                }
            }
        }
    } else {
#pragma unroll
        for (int mi = 0; mi < 4; mi++)
#pragma unroll
            for (int r = 0; r < 4; r++) {
                int m = m0 + wr * 64 + mi * 16 + lg * 4 + r;
#pragma unroll
                for (int ni = 0; ni < 4; ni++) {
                    int n = n0 + wc * 64 + ni * 16 + lm;
                    C[(long)m * 1024 + n] = acc[mi][ni][r];
                }
            }
    }
}

// ---------------------------------------------------------------------------
// Kernel 2: MFMA flash attention. r12 shell (QBLK=64 per block, grid 1024,
// XCD swizzle, double-buffered K/V DMA, one barrier/tile) with the 32x32x16
// + in-register-P core (r8-verified layouts): 4 waves split 2x2 over
// (q-half qi, key-half ki); each wave = 32q x 32keys/tile = 8 ds_read_b128
// feeding 8 MFMA (vs 16 reads/16 half-FLOP MFMA before), P never in LDS
// (cvt_pk + permlane32_swap), -8*log2e folded into the QK accumulator INIT
// (no per-score subtract). Key-halves combined once at the end via
// lane-major (conflict-free) LDS.
// ---------------------------------------------------------------------------
__global__ __launch_bounds__(256, 4) void attn_mfma(
    const __hip_bfloat16* __restrict__ Q,
    const __hip_bfloat16* __restrict__ K,
    const __hip_bfloat16* __restrict__ Vt,  // [B,H,D,S]
    __hip_bfloat16* __restrict__ O)
{
    __shared__ __align__(16) char Ksh[2][64 * 128];  // 64 keys x 64 d (swz)
    __shared__ __align__(16) char Vsh[2][64 * 128];  // 64 d x 64 keys (swz)

    // XCD swizzle (r12-proven): XCD x owns heads bh === x (mod 8).
    const int L  = blockIdx.x;               // 0..1023
    const int bh = (L & 7) + (L >> 8) * 8;
    const int q0 = ((L >> 3) & 31) * 64;
    const int b  = bh >> 4, h = bh & 15;
    const int t  = threadIdx.x;
    const int w  = t >> 6;                   // wave 0..3
    const int qi = w & 1;                    // q-half (32 rows)
    const int ki = w >> 1;                   // key-half (32 keys)
    const int l  = t & 63;
    const int lo5 = l & 31;
    const int hi  = l >> 5;

    // Q fragments (pre-scaled by 0.125*log2e): q = q0 + qi*32 + lo5
    const char* Qr =
        (const char*)(Q + ((long)bh * S_LEN + q0 + qi * 32 + lo5) * HD);
    bf16x8 qf[4];
#pragma unroll
    for (int ks = 0; ks < 4; ks++)
        qf[ks] = *(const bf16x8*)(Qr + ks * 32 + hi * 16);

    f32x16 oacc[2] = {};
    float lsum = 0.f;
    const float EXPB = 11.54156033f;  // 8 * log2(e)

    const char* Kgb = (const char*)(K + (long)bh * S_LEN * HD);
    const char* Vgb = (const char*)(Vt + (long)bh * HD * S_LEN);

    // DMA staging (r12-proven): lane l covers LDS row w*8+(l>>3) (+32 chunk2),
    // 16B col (l&7). Linear LDS dest; source byte pre-swizzled by ((row&7)<<4).
    const int swb = ((l & 7) * 16) ^ (((l >> 3) & 7) << 4);
    const int row0 = w * 8 + (l >> 3);
    const char* Ksrc  = Kgb + (long)row0 * 128 + swb;                  // +kt*128
    const char* Vsrc0 = Vgb + (long)row0 * (S_LEN * 2) + swb;          // +kt*2
    const char* Vsrc1 = Vgb + (long)(row0 + 32) * (S_LEN * 2) + swb;   // +kt*2

    // prologue: stage tile 0 into buffer 0
    gload_lds16(Ksrc, Ksh[0] + w * 1024);
    gload_lds16(Ksrc + 32 * 128, Ksh[0] + w * 1024 + 4096);
    gload_lds16(Vsrc0, Vsh[0] + w * 1024);
    gload_lds16(Vsrc1, Vsh[0] + w * 1024 + 4096);

    const int swr = (lo5 & 7) << 4;  // read swizzle (row&7 == lo5&7 here)
    int cur = 0;
    for (int kt = 0; kt < S_LEN; kt += 64) {
        __syncthreads();  // vmcnt(0) drained -> buf[cur] staged; alt reads done

        if (kt + 64 < S_LEN) {  // stage next tile into alternate buffer
            int nk = kt + 64;
            gload_lds16(Ksrc + (long)nk * 128, Ksh[cur ^ 1] + w * 1024);
            gload_lds16(Ksrc + (long)(nk + 32) * 128, Ksh[cur ^ 1] + w * 1024 + 4096);
            gload_lds16(Vsrc0 + (long)nk * 2, Vsh[cur ^ 1] + w * 1024);
            gload_lds16(Vsrc1 + (long)nk * 2, Vsh[cur ^ 1] + w * 1024 + 4096);
        }

        const char* Kc = Ksh[cur];
        const char* Vc = Vsh[cur];

        // ---- S^T - EXPB = K Q^T + (-EXPB): acc INIT carries the bias ----
        f32x16 s;
#pragma unroll
        for (int r = 0; r < 16; r++) s[r] = -EXPB;
        const char* Krow = Kc + (ki * 32 + lo5) * 128;
        __builtin_amdgcn_s_setprio(1);
#pragma unroll
        for (int ks = 0; ks < 4; ks++) {
            bf16x8 kf = *(const bf16x8*)(Krow + ((ks * 32 + hi * 16) ^ swr));
            s = __builtin_amdgcn_mfma_f32_32x32x16_bf16(kf, qf[ks], s, 0, 0, 0);
        }
        __builtin_amdgcn_s_setprio(0);
        // s[r] = S[key=ki*32+(r&3)+8*(r>>2)+4*hi][q=lo5] - EXPB

        // ---- softmax + in-register P->PA (cvt_pk + permlane, r8-verified) --
        float p[16];
#pragma unroll
        for (int r = 0; r < 16; r++) p[r] = __builtin_amdgcn_exp2f(s[r]);
#pragma unroll
        for (int r = 0; r < 16; r += 4)
            lsum += (p[r] + p[r + 1]) + (p[r + 2] + p[r + 3]);
        unsigned c0, c1, c2, c3, c4, c5, c6, c7;
        asm("v_cvt_pk_bf16_f32 %0, %1, %2" : "=v"(c0) : "v"(p[0]),  "v"(p[1]));
        asm("v_cvt_pk_bf16_f32 %0, %1, %2" : "=v"(c1) : "v"(p[2]),  "v"(p[3]));
        asm("v_cvt_pk_bf16_f32 %0, %1, %2" : "=v"(c2) : "v"(p[4]),  "v"(p[5]));
        asm("v_cvt_pk_bf16_f32 %0, %1, %2" : "=v"(c3) : "v"(p[6]),  "v"(p[7]));
        asm("v_cvt_pk_bf16_f32 %0, %1, %2" : "=v"(c4) : "v"(p[8]),  "v"(p[9]));
        asm("v_cvt_pk_bf16_f32 %0, %1, %2" : "=v"(c5) : "v"(p[10]), "v"(p[11]));
        asm("v_cvt_pk_bf16_f32 %0, %1, %2" : "=v"(c6) : "v"(p[12]), "v"(p[13]));
        asm("v_cvt_pk_bf16_f32 %0, %1, %2" : "=v"(c7) : "v"(p[14]), "v"(p[15]));
        asm("v_permlane32_swap_b32 %0, %1" : "+v"(c0), "+v"(c2));
        asm("v_permlane32_swap_b32 %0, %1" : "+v"(c1), "+v"(c3));
        asm("v_permlane32_swap_b32 %0, %1" : "+v"(c4), "+v"(c6));
        asm("v_permlane32_swap_b32 %0, %1" : "+v"(c5), "+v"(c7));
        u32x4 w0 = {c0, c1, c2, c3};
        u32x4 w1 = {c4, c5, c6, c7};
        bf16x8 pa0 = __builtin_bit_cast(bf16x8, w0);  // keys ki*32 + 0..15
        bf16x8 pa1 = __builtin_bit_cast(bf16x8, w1);  // keys ki*32 + 16..31

        // ---- O += P V over this wave's 32 keys ----
        __builtin_amdgcn_s_setprio(1);
#pragma unroll
        for (int db = 0; db < 2; db++) {
            const char* Vrow = Vc + (db * 32 + lo5) * 128;
            bf16x8 vf0 = *(const bf16x8*)(Vrow + ((ki * 64 + hi * 16) ^ swr));
            bf16x8 vf1 = *(const bf16x8*)(Vrow + ((ki * 64 + 32 + hi * 16) ^ swr));
            oacc[db] = __builtin_amdgcn_mfma_f32_32x32x16_bf16(pa0, vf0, oacc[db], 0, 0, 0);
            oacc[db] = __builtin_amdgcn_mfma_f32_32x32x16_bf16(pa1, vf1, oacc[db], 0, 0, 0);
        }
        __builtin_amdgcn_s_setprio(0);
        cur ^= 1;
    }

    // ---- combine key-halves: lane lo5 holds q=lo5 after hi-reduce ----
    lsum += __shfl_xor(lsum, 32, 64);
    __syncthreads();  // main-loop LDS reads done; reuse Ksh/Vsh
    float* Osh = (float*)Ksh;        // 2 qi regions x 32x64 floats = 16 KB
    float* Lsh = (float*)Vsh;        // 2 qi regions x 64 floats
    if (ki == 1) {
        float* dst = Osh + qi * 2048;
#pragma unroll
        for (int db = 0; db < 2; db++)
#pragma unroll
            for (int r = 0; r < 16; r++)
                dst[(db * 16 + r) * 64 + l] = oacc[db][r];  // lane-major: no conflicts
        Lsh[qi * 64 + l] = lsum;
    }
    __syncthreads();
    if (ki == 0) {
        const float* src = Osh + qi * 2048;
#pragma unroll
        for (int db = 0; db < 2; db++)
#pragma unroll
            for (int r = 0; r < 16; r++)
                oacc[db][r] += src[(db * 16 + r) * 64 + l];
        lsum += Lsh[qi * 64 + l];
        float inv = 1.f / lsum;  // valid for q = lo5
#pragma unroll
        for (int r = 0; r < 16; r++) {
            int qr = (r & 3) + 8 * (r >> 2) + 4 * hi;
            float invr = __shfl(inv, qr, 32);
            int qrow = q0 + qi * 32 + qr;
            long base = ((long)b * S_LEN + qrow) * EMB + h * HD;
            O[base + lo5]      = __float2bfloat16(oacc[0][r] * invr);
            O[base + 32 + lo5] = __float2bfloat16(oacc[1][r] * invr);
        }
    }
}

extern "C" void kernel_launch(void* const* d_in, const int* in_sizes, int n_in,
                              void* d_out, int out_size, void* d_ws, size_t ws_size,
                              hipStream_t stream) {
    const float* x     = (const float*)d_in[0];   // [2,2048,1024]
    const float* qkv_w = (const float*)d_in[1];   // [3072,1024]
    const float* out_w = (const float*)d_in[2];   // [1024,1024]
    const float* qp    = (const float*)d_in[3];   // [64]
    float* out = (float*)d_out;                   // [2,2048,1024] fp32

    const long NELEM = (long)2 * S_LEN * EMB;     // 4,194,304
    __hip_bfloat16* Q   = (__hip_bfloat16*)d_ws;  // [B,H,S,D] (x 0.125*log2e)
    __hip_bfloat16* K   = Q + NELEM;              // [B,H,S,D]
    __hip_bfloat16* Vt  = K + NELEM;              // [B,H,D,S]
    __hip_bfloat16* O   = Vt + NELEM;             // [B,S,E]
    __hip_bfloat16* xb  = O + NELEM;              // [4096][1024]
    __hip_bfloat16* wqb = xb + NELEM;             // [3072][1024]
    __hip_bfloat16* wob = wqb + (long)3072 * 1024;// [1024][1024]

    dim3 blk(256);
    cvt_all<<<dim3(8192), blk, 0, stream>>>(x, qkv_w, out_w, xb, wqb, wob);
    gemm_mfma<0><<<dim3(3072 / 128, 4096 / 128), blk, 0, stream>>>(
        xb, wqb, qp, Q, K, Vt, nullptr);
    attn_mfma<<<dim3(1024), blk, 0, stream>>>(Q, K, Vt, O);
    gemm_mfma<1><<<dim3(1024 / 128, 4096 / 128), blk, 0, stream>>>(
        O, wob, nullptr, nullptr, nullptr, nullptr, out);
}

// Round 14
// 116.970 us; speedup vs baseline: 1.4948x; 1.0091x over previous
//
#include <hip/hip_runtime.h>
#include <hip/hip_bf16.h>

#define S_LEN 2048
#define EMB 1024
#define NH 16
#define HD 64
// M = B*S = 4096 rows

typedef __attribute__((ext_vector_type(8))) __bf16 bf16x8;
typedef __attribute__((ext_vector_type(4))) float f32x4;
typedef __attribute__((ext_vector_type(16))) float f32x16;
typedef __attribute__((ext_vector_type(4))) unsigned int u32x4;

__device__ inline void gload_lds16(const void* g, void* l) {
    __builtin_amdgcn_global_load_lds(
        (const __attribute__((address_space(1))) unsigned int*)g,
        (__attribute__((address_space(3))) unsigned int*)l, 16, 0, 0);
}

// ---------------------------------------------------------------------------
// Kernel 0: fp32 -> bf16 conversion of x, qkv_w, out_w in ONE launch.
// ---------------------------------------------------------------------------
__global__ __launch_bounds__(256) void cvt_all(
    const float* __restrict__ x, const float* __restrict__ wq,
    const float* __restrict__ wo,
    __hip_bfloat16* __restrict__ xb, __hip_bfloat16* __restrict__ wqb,
    __hip_bfloat16* __restrict__ wob)
{
    const long C_X = (long)4096 * 1024 / 4;       // 1,048,576
    const long C_WQ = (long)3072 * 1024 / 4;      // 786,432
    long c = (long)blockIdx.x * 256 + threadIdx.x;
    const float* in;
    __hip_bfloat16* out;
    if (c < C_X) { in = x; out = xb; }
    else if (c < C_X + C_WQ) { in = wq; out = wqb; c -= C_X; }
    else { in = wo; out = wob; c -= C_X + C_WQ; }
    long i = c * 4;
    float4 v = *(const float4*)(in + i);
    __hip_bfloat16 b0 = __float2bfloat16(v.x);
    __hip_bfloat16 b1 = __float2bfloat16(v.y);
    __hip_bfloat16 b2 = __float2bfloat16(v.z);
    __hip_bfloat16 b3 = __float2bfloat16(v.w);
    ushort4 o = {*(unsigned short*)&b0, *(unsigned short*)&b1,
                 *(unsigned short*)&b2, *(unsigned short*)&b3};
    *(ushort4*)(out + i) = o;
}

// ---------------------------------------------------------------------------
// MFMA GEMM core (m97 structure): C = A @ B^T, BM=128, BN templated, BK=64,
// 4 waves (2x2; wave covers 64 rows x BN/2 cols). 1-D grid with bijective
// XCD swizzle (T1): sw = (bid&7)*CH + bid>>3; x = sw%NX, y = sw/NX.
// EPI=0 (BN=128): quantum epilogue (cos*cos, scatter Q/K/Vt; V via per-wave
// LDS transpose).  EPI=1 (BN=64): fp32 C store, 512 blocks -> 2/CU.
// Q is pre-scaled by 0.125*log2(e) so attention can use exp2 directly.
// ---------------------------------------------------------------------------
template <int EPI, int BN, int NX, int CH>
__global__ __launch_bounds__(256) void gemm_mfma(
    const __hip_bfloat16* __restrict__ A,   // [M][1024]
    const __hip_bfloat16* __restrict__ B,   // [N][1024]
    const float* __restrict__ qp,           // [64] (EPI=0)
    __hip_bfloat16* __restrict__ Q,         // EPI=0 outputs
    __hip_bfloat16* __restrict__ Kp,
    __hip_bfloat16* __restrict__ Vt,
    float* __restrict__ C)                  // EPI=1 output
{
    const int Kd = 1024;
    const int NI = BN / 32;                 // 16-col frags per wave
    __shared__ __align__(16) char Ash[128 * 128];
    __shared__ __align__(16) char Bsh[BN * 128];

    const int bid = blockIdx.x;
    const int sw_ = (bid & 7) * CH + (bid >> 3);
    const int m0 = (sw_ / NX) * 128;
    const int n0 = (sw_ % NX) * BN;

    const int t  = threadIdx.x;
    const int w  = t >> 6;
    const int l  = t & 63;
    const int lg = l >> 4, lm = l & 15;
    const int wr = w >> 1, wc = w & 1;

    const int r8 = l >> 3;
    const int sb = ((l & 7) * 16) ^ (r8 << 4);
    const char* srcA = (const char*)A + ((long)(m0 + w * 32 + r8) * Kd) * 2 + sb;
    const char* srcB = (const char*)B + ((long)(n0 + w * (BN / 4) + r8) * Kd) * 2 + sb;

    f32x4 acc[4][NI];
#pragma unroll
    for (int i = 0; i < 4; i++)
#pragma unroll
        for (int j = 0; j < NI; j++) acc[i][j] = (f32x4){0.f, 0.f, 0.f, 0.f};

    for (int kt = 0; kt < Kd * 2; kt += 128) {
#pragma unroll
        for (int j = 0; j < 4; j++)
            gload_lds16(srcA + (long)j * 8 * Kd * 2 + kt, Ash + (w * 32 + j * 8) * 128);
#pragma unroll
        for (int j = 0; j < NI; j++)
            gload_lds16(srcB + (long)j * 8 * Kd * 2 + kt,
                        Bsh + (w * (BN / 4) + j * 8) * 128);
        __syncthreads();
#pragma unroll
        for (int kk = 0; kk < 2; kk++) {
            bf16x8 af[4], bfr[NI];
            const int sw = (lm & 7) << 4;
            const int co = (kk * 64 + lg * 16);
#pragma unroll
            for (int mi = 0; mi < 4; mi++)
                af[mi] = *(const bf16x8*)(Ash + (wr * 64 + mi * 16 + lm) * 128 + (co ^ sw));
#pragma unroll
            for (int ni = 0; ni < NI; ni++)
                bfr[ni] = *(const bf16x8*)(Bsh + (wc * (BN / 2) + ni * 16 + lm) * 128 + (co ^ sw));
#pragma unroll
            for (int mi = 0; mi < 4; mi++)
#pragma unroll
                for (int ni = 0; ni < NI; ni++)
                    acc[mi][ni] = __builtin_amdgcn_mfma_f32_16x16x32_bf16(
                        af[mi], bfr[ni], acc[mi][ni], 0, 0, 0);
        }
        __syncthreads();
    }

    if constexpr (EPI == 0) {
        const int which = n0 >> 10;
        float cqp[NI];
#pragma unroll
        for (int ni = 0; ni < NI; ni++)
            cqp[ni] = __cosf(qp[(wc * (BN / 2) + ni * 16 + lm) & 63]);

        if (which == 2) {
            // ---- V: per-wave LDS transpose -> coalesced Vt[d][s] stores ----
            char* T = (w < 2 ? Ash : Bsh) + (w & 1) * 8192;
#pragma unroll
            for (int mi = 0; mi < 4; mi++)
#pragma unroll
                for (int r = 0; r < 4; r++)
#pragma unroll
                    for (int ni = 0; ni < NI; ni++) {
                        int row = ni * 16 + lm;            // d (0..63)
                        int col = mi * 16 + lg * 4 + r;    // s-local (0..63)
                        float val = __cosf(acc[mi][ni][r]) * cqp[ni];
                        *(__hip_bfloat16*)(T + row * 128 +
                                           ((col * 2) ^ ((row & 7) << 4))) =
                            __float2bfloat16(val);
                    }
            const int h  = ((n0 & 1023) >> 6) + wc;
            const int bh = (m0 >> 11) * NH + h;
            const int sbase = (m0 & 2047) + wr * 64;
#pragma unroll
            for (int j = 0; j < 8; j++) {
                int c = j * 64 + l;
                int d = c >> 3;
                int sc = (c & 7) * 16;
                uint4 v = *(const uint4*)(T + d * 128 + (sc ^ ((d & 7) << 4)));
                *(uint4*)((char*)(Vt + ((long)bh * HD + d) * S_LEN + sbase) + sc) = v;
            }
        } else {
#pragma unroll
            for (int mi = 0; mi < 4; mi++) {
#pragma unroll
                for (int r = 0; r < 4; r++) {
                    int m = m0 + wr * 64 + mi * 16 + lg * 4 + r;
                    int b = m >> 11, s = m & 2047;
#pragma unroll
                    for (int ni = 0; ni < NI; ni++) {
                        int n = n0 + wc * (BN / 2) + ni * 16 + lm;
                        int d = n & 63;
                        int h = (n & 1023) >> 6;
                        int bh = b * NH + h;
                        float val = __cosf(acc[mi][ni][r]) * cqp[ni];
                        if (which == 0)  // 0.125*log2(e) folded for exp2 softmax
                            Q[((long)bh * S_LEN + s) * HD + d] =
                                __float2bfloat16(val * 0.180336880f);
                        else
                            Kp[((long)bh * S_LEN + s) * HD + d] = __float2bfloat16(val);
                    }
                }
            }
        }
    } else {
#pragma unroll
        for (int mi = 0; mi < 4; mi++)
#pragma unroll
            for (int r = 0; r < 4; r++) {
                int m = m0 + wr * 64 + mi * 16 + lg * 4 + r;
#pragma unroll
                for (int ni = 0; ni < NI; ni++) {
                    int n = n0 + wc * (BN / 2) + ni * 16 + lm;
                    C[(long)m * 1024 + n] = acc[mi][ni][r];
                }
            }
    }
}

// ---------------------------------------------------------------------------
// Kernel 2: MFMA flash attention. KVBLK=128 per round (2 sub-tiles of 64
// keys), 4 waves = 4 KEY-quarters; each wave computes BOTH q-halves (64 q,
// 2 fragments) from ONE kf/vf read -> LDS reads per key halved vs r13
// (8 ds_read_b128 feed 16 MFMA per wave-round), barriers per key halved.
// Double-buffered DMA staging (r13 scheme), 65KB LDS -> 2 blocks/CU.
// In-register P (cvt_pk+permlane, r8-verified); -8*log2e in acc init.
// Final: 4-way partial-O combine in fp32 through the dead staging LDS.
// ---------------------------------------------------------------------------
__global__ __launch_bounds__(256, 2) void attn_mfma(
    const __hip_bfloat16* __restrict__ Q,
    const __hip_bfloat16* __restrict__ K,
    const __hip_bfloat16* __restrict__ Vt,  // [B,H,D,S]
    __hip_bfloat16* __restrict__ O)
{
    __shared__ __align__(16) char smem[65536 + 1024];
    // K sub-tile (buf,sp): smem + (buf*2+sp)*8192        (64 keys x 128B, swz)
    // V sub-tile (buf,sp): smem + 32768 + (buf*2+sp)*8192 (64 d x 128B, swz)
    // combine: Osh = (float*)smem (64KB), Lsh = (float*)(smem + 65536)

    const int L  = blockIdx.x;               // 0..1023
    const int bh = (L & 7) + (L >> 8) * 8;   // XCD swizzle (r12-proven)
    const int q0 = ((L >> 3) & 31) * 64;
    const int b  = bh >> 4, h = bh & 15;
    const int t  = threadIdx.x;
    const int w  = t >> 6;                   // key-quarter 0..3
    const int sp = w >> 1, kh = w & 1;       // sub-tile, key-half within it
    const int l  = t & 63;
    const int lo5 = l & 31;
    const int hi  = l >> 5;

    // Q fragments (pre-scaled by 0.125*log2e): g in {0,1} -> q = g*32 + lo5
    bf16x8 qf[2][4];
#pragma unroll
    for (int g = 0; g < 2; g++) {
        const char* Qr = (const char*)(Q + ((long)bh * S_LEN + q0 + g * 32 + lo5) * HD);
#pragma unroll
        for (int ks = 0; ks < 4; ks++)
            qf[g][ks] = *(const bf16x8*)(Qr + ks * 32 + hi * 16);
    }

    f32x16 oacc[2][2] = {};
    float lsum[2] = {0.f, 0.f};
    const float EXPB = 11.54156033f;  // 8 * log2(e)

    const char* Kgb = (const char*)(K + (long)bh * S_LEN * HD);
    const char* Vgb = (const char*)(Vt + (long)bh * HD * S_LEN);

    // DMA staging (r13-proven geometry): all 4 waves stage their 8-row slice
    // of BOTH sub-tiles. Linear LDS dest; source pre-swizzled ((row&7)<<4).
    const int swb = ((l & 7) * 16) ^ (((l >> 3) & 7) << 4);
    const int row0 = w * 8 + (l >> 3);
    const char* Ksrc  = Kgb + (long)row0 * 128 + swb;                  // +key*128
    const char* Vsrc0 = Vgb + (long)row0 * (S_LEN * 2) + swb;          // +key*2
    const char* Vsrc1 = Vgb + (long)(row0 + 32) * (S_LEN * 2) + swb;   // +key*2

#define STAGE(buf, nk)                                                         \
    do {                                                                       \
        _Pragma("unroll") for (int sp2 = 0; sp2 < 2; sp2++) {                  \
            char* Kd_ = smem + ((buf) * 2 + sp2) * 8192;                       \
            char* Vd_ = smem + 32768 + ((buf) * 2 + sp2) * 8192;               \
            int kb = (nk) + sp2 * 64;                                          \
            gload_lds16(Ksrc + (long)kb * 128, Kd_ + w * 1024);                \
            gload_lds16(Ksrc + (long)(kb + 32) * 128, Kd_ + w * 1024 + 4096);  \
            gload_lds16(Vsrc0 + (long)kb * 2, Vd_ + w * 1024);                 \
            gload_lds16(Vsrc1 + (long)kb * 2, Vd_ + w * 1024 + 4096);          \
        }                                                                      \
    } while (0)

    STAGE(0, 0);

    const int swr = (lo5 & 7) << 4;
    int cur = 0;
    for (int rd = 0; rd < 16; rd++) {
        __syncthreads();  // drains prev-round stage (full compute to land)

        if (rd < 15) STAGE(cur ^ 1, (rd + 1) * 128);

        const char* Kc = smem + (cur * 2 + sp) * 8192;
        const char* Vc = smem + 32768 + (cur * 2 + sp) * 8192;

        // ---- S^T - EXPB = K Q^T (one kf read feeds both q-frags) ----
        f32x16 s0, s1;
#pragma unroll
        for (int r = 0; r < 16; r++) { s0[r] = -EXPB; s1[r] = -EXPB; }
        const char* Krow = Kc + (kh * 32 + lo5) * 128;
        __builtin_amdgcn_s_setprio(1);
#pragma unroll
        for (int ks = 0; ks < 4; ks++) {
            bf16x8 kf = *(const bf16x8*)(Krow + ((ks * 32 + hi * 16) ^ swr));
            s0 = __builtin_amdgcn_mfma_f32_32x32x16_bf16(kf, qf[0][ks], s0, 0, 0, 0);
            s1 = __builtin_amdgcn_mfma_f32_32x32x16_bf16(kf, qf[1][ks], s1, 0, 0, 0);
        }
        __builtin_amdgcn_s_setprio(0);

        // ---- softmax + in-register P (cvt_pk + permlane), per q-frag ----
        bf16x8 pa[2][2];
#pragma unroll
        for (int g = 0; g < 2; g++) {
            const f32x16& sv = g ? s1 : s0;
            float p[16];
#pragma unroll
            for (int r = 0; r < 16; r++) p[r] = __builtin_amdgcn_exp2f(sv[r]);
#pragma unroll
            for (int r = 0; r < 16; r += 4)
                lsum[g] += (p[r] + p[r + 1]) + (p[r + 2] + p[r + 3]);
            unsigned c0, c1, c2, c3, c4, c5, c6, c7;
            asm("v_cvt_pk_bf16_f32 %0, %1, %2" : "=v"(c0) : "v"(p[0]),  "v"(p[1]));
            asm("v_cvt_pk_bf16_f32 %0, %1, %2" : "=v"(c1) : "v"(p[2]),  "v"(p[3]));
            asm("v_cvt_pk_bf16_f32 %0, %1, %2" : "=v"(c2) : "v"(p[4]),  "v"(p[5]));
            asm("v_cvt_pk_bf16_f32 %0, %1, %2" : "=v"(c3) : "v"(p[6]),  "v"(p[7]));
            asm("v_cvt_pk_bf16_f32 %0, %1, %2" : "=v"(c4) : "v"(p[8]),  "v"(p[9]));
            asm("v_cvt_pk_bf16_f32 %0, %1, %2" : "=v"(c5) : "v"(p[10]), "v"(p[11]));
            asm("v_cvt_pk_bf16_f32 %0, %1, %2" : "=v"(c6) : "v"(p[12]), "v"(p[13]));
            asm("v_cvt_pk_bf16_f32 %0, %1, %2" : "=v"(c7) : "v"(p[14]), "v"(p[15]));
            asm("v_permlane32_swap_b32 %0, %1" : "+v"(c0), "+v"(c2));
            asm("v_permlane32_swap_b32 %0, %1" : "+v"(c1), "+v"(c3));
            asm("v_permlane32_swap_b32 %0, %1" : "+v"(c4), "+v"(c6));
            asm("v_permlane32_swap_b32 %0, %1" : "+v"(c5), "+v"(c7));
            u32x4 w0 = {c0, c1, c2, c3};
            u32x4 w1 = {c4, c5, c6, c7};
            pa[g][0] = __builtin_bit_cast(bf16x8, w0);  // wave's keys 0..15
            pa[g][1] = __builtin_bit_cast(bf16x8, w1);  // wave's keys 16..31
        }

        // ---- O += P V (one vf read feeds both q-frags) ----
        __builtin_amdgcn_s_setprio(1);
#pragma unroll
        for (int db = 0; db < 2; db++) {
            const char* Vrow = Vc + (db * 32 + lo5) * 128;
            bf16x8 vf0 = *(const bf16x8*)(Vrow + ((kh * 64 + hi * 16) ^ swr));
            bf16x8 vf1 = *(const bf16x8*)(Vrow + ((kh * 64 + 32 + hi * 16) ^ swr));
            oacc[0][db] = __builtin_amdgcn_mfma_f32_32x32x16_bf16(pa[0][0], vf0, oacc[0][db], 0, 0, 0);
            oacc[0][db] = __builtin_amdgcn_mfma_f32_32x32x16_bf16(pa[0][1], vf1, oacc[0][db], 0, 0, 0);
            oacc[1][db] = __builtin_amdgcn_mfma_f32_32x32x16_bf16(pa[1][0], vf0, oacc[1][db], 0, 0, 0);
            oacc[1][db] = __builtin_amdgcn_mfma_f32_32x32x16_bf16(pa[1][1], vf1, oacc[1][db], 0, 0, 0);
        }
        __builtin_amdgcn_s_setprio(0);
        cur ^= 1;
    }
#undef STAGE

    // ---- combine 4 key-quarter partials through LDS (fp32) ----
#pragma unroll
    for (int g = 0; g < 2; g++) lsum[g] += __shfl_xor(lsum[g], 32, 64);
    __syncthreads();  // all staging reads done; smem reusable
    float* Osh = (float*)smem;               // [4 waves][64 q][64 d]
    float* Lsh = (float*)(smem + 65536);     // [4 waves][64 q]
#pragma unroll
    for (int g = 0; g < 2; g++)
#pragma unroll
        for (int db = 0; db < 2; db++)
#pragma unroll
            for (int r = 0; r < 16; r++) {
                int q = g * 32 + (r & 3) + 8 * (r >> 2) + 4 * hi;
                Osh[w * 4096 + q * 64 + db * 32 + lo5] = oacc[g][db][r];
            }
    if (l < 32) {
        Lsh[w * 64 + lo5]      = lsum[0];
        Lsh[w * 64 + 32 + lo5] = lsum[1];
    }
    __syncthreads();
    // wave w finalizes q-rows w*16..w*16+15; lane l = d
#pragma unroll
    for (int i = 0; i < 16; i++) {
        int qh = w * 16 + i;
        float Lq = Lsh[qh] + Lsh[64 + qh] + Lsh[128 + qh] + Lsh[192 + qh];
        float v = Osh[qh * 64 + l] + Osh[4096 + qh * 64 + l] +
                  Osh[8192 + qh * 64 + l] + Osh[12288 + qh * 64 + l];
        O[((long)b * S_LEN + q0 + qh) * EMB + h * HD + l] =
            __float2bfloat16(v * (1.f / Lq));
    }
}

extern "C" void kernel_launch(void* const* d_in, const int* in_sizes, int n_in,
                              void* d_out, int out_size, void* d_ws, size_t ws_size,
                              hipStream_t stream) {
    const float* x     = (const float*)d_in[0];   // [2,2048,1024]
    const float* qkv_w = (const float*)d_in[1];   // [3072,1024]
    const float* out_w = (const float*)d_in[2];   // [1024,1024]
    const float* qp    = (const float*)d_in[3];   // [64]
    float* out = (float*)d_out;                   // [2,2048,1024] fp32

    const long NELEM = (long)2 * S_LEN * EMB;     // 4,194,304
    __hip_bfloat16* Q   = (__hip_bfloat16*)d_ws;  // [B,H,S,D] (x 0.125*log2e)
    __hip_bfloat16* K   = Q + NELEM;              // [B,H,S,D]
    __hip_bfloat16* Vt  = K + NELEM;              // [B,H,D,S]
    __hip_bfloat16* O   = Vt + NELEM;             // [B,S,E]
    __hip_bfloat16* xb  = O + NELEM;              // [4096][1024]
    __hip_bfloat16* wqb = xb + NELEM;             // [3072][1024]
    __hip_bfloat16* wob = wqb + (long)3072 * 1024;// [1024][1024]

    dim3 blk(256);
    cvt_all<<<dim3(8192), blk, 0, stream>>>(x, qkv_w, out_w, xb, wqb, wob);
    // EPI=0: BN=128, grid 24x32=768 (1-D, XCD-swizzled: CH=96)
    gemm_mfma<0, 128, 24, 96><<<dim3(768), blk, 0, stream>>>(
        xb, wqb, qp, Q, K, Vt, nullptr);
    attn_mfma<<<dim3(1024), blk, 0, stream>>>(Q, K, Vt, O);
    // EPI=1: BN=64, grid 16x32=512 (2 blocks/CU; CH=64)
    gemm_mfma<1, 64, 16, 64><<<dim3(512), blk, 0, stream>>>(
        O, wob, nullptr, nullptr, nullptr, nullptr, out);
}

// Round 15
// 115.729 us; speedup vs baseline: 1.5108x; 1.0107x over previous
//
#include <hip/hip_runtime.h>
#include <hip/hip_bf16.h>

#define S_LEN 2048
#define EMB 1024
#define NH 16
#define HD 64
// M = B*S = 4096 rows

typedef __attribute__((ext_vector_type(8))) __bf16 bf16x8;
typedef __attribute__((ext_vector_type(4))) float f32x4;
typedef __attribute__((ext_vector_type(16))) float f32x16;
typedef __attribute__((ext_vector_type(4))) unsigned int u32x4;

__device__ inline void gload_lds16(const void* g, void* l) {
    __builtin_amdgcn_global_load_lds(
        (const __attribute__((address_space(1))) unsigned int*)g,
        (__attribute__((address_space(3))) unsigned int*)l, 16, 0, 0);
}

// ---------------------------------------------------------------------------
// Kernel 0: fp32 -> bf16 conversion of x, qkv_w, out_w in ONE launch.
// ---------------------------------------------------------------------------
__global__ __launch_bounds__(256) void cvt_all(
    const float* __restrict__ x, const float* __restrict__ wq,
    const float* __restrict__ wo,
    __hip_bfloat16* __restrict__ xb, __hip_bfloat16* __restrict__ wqb,
    __hip_bfloat16* __restrict__ wob)
{
    const long C_X = (long)4096 * 1024 / 4;       // 1,048,576
    const long C_WQ = (long)3072 * 1024 / 4;      // 786,432
    long c = (long)blockIdx.x * 256 + threadIdx.x;
    const float* in;
    __hip_bfloat16* out;
    if (c < C_X) { in = x; out = xb; }
    else if (c < C_X + C_WQ) { in = wq; out = wqb; c -= C_X; }
    else { in = wo; out = wob; c -= C_X + C_WQ; }
    long i = c * 4;
    float4 v = *(const float4*)(in + i);
    __hip_bfloat16 b0 = __float2bfloat16(v.x);
    __hip_bfloat16 b1 = __float2bfloat16(v.y);
    __hip_bfloat16 b2 = __float2bfloat16(v.z);
    __hip_bfloat16 b3 = __float2bfloat16(v.w);
    ushort4 o = {*(unsigned short*)&b0, *(unsigned short*)&b1,
                 *(unsigned short*)&b2, *(unsigned short*)&b3};
    *(ushort4*)(out + i) = o;
}

// ---------------------------------------------------------------------------
// MFMA GEMM core (m97 structure): C = A @ B^T, BM=128, BN templated, BK=64,
// 4 waves (2x2; wave covers 64 rows x BN/2 cols). 1-D grid with bijective
// XCD swizzle (T1): sw = (bid&7)*CH + bid>>3; x = sw%NX, y = sw/NX.
// EPI=0 (BN=128): quantum epilogue (cos*cos, scatter Q/K/Vt; V via per-wave
// LDS transpose).  EPI=1 (BN=64): fp32 C store, 512 blocks -> 2/CU.
// Q is pre-scaled by 0.125*log2(e) so attention can use exp2 directly.
// ---------------------------------------------------------------------------
template <int EPI, int BN, int NX, int CH>
__global__ __launch_bounds__(256) void gemm_mfma(
    const __hip_bfloat16* __restrict__ A,   // [M][1024]
    const __hip_bfloat16* __restrict__ B,   // [N][1024]
    const float* __restrict__ qp,           // [64] (EPI=0)
    __hip_bfloat16* __restrict__ Q,         // EPI=0 outputs
    __hip_bfloat16* __restrict__ Kp,
    __hip_bfloat16* __restrict__ Vt,
    float* __restrict__ C)                  // EPI=1 output
{
    const int Kd = 1024;
    const int NI = BN / 32;                 // 16-col frags per wave
    __shared__ __align__(16) char Ash[128 * 128];
    __shared__ __align__(16) char Bsh[BN * 128];

    const int bid = blockIdx.x;
    const int sw_ = (bid & 7) * CH + (bid >> 3);
    const int m0 = (sw_ / NX) * 128;
    const int n0 = (sw_ % NX) * BN;

    const int t  = threadIdx.x;
    const int w  = t >> 6;
    const int l  = t & 63;
    const int lg = l >> 4, lm = l & 15;
    const int wr = w >> 1, wc = w & 1;

    const int r8 = l >> 3;
    const int sb = ((l & 7) * 16) ^ (r8 << 4);
    const char* srcA = (const char*)A + ((long)(m0 + w * 32 + r8) * Kd) * 2 + sb;
    const char* srcB = (const char*)B + ((long)(n0 + w * (BN / 4) + r8) * Kd) * 2 + sb;

    f32x4 acc[4][NI];
#pragma unroll
    for (int i = 0; i < 4; i++)
#pragma unroll
        for (int j = 0; j < NI; j++) acc[i][j] = (f32x4){0.f, 0.f, 0.f, 0.f};

    for (int kt = 0; kt < Kd * 2; kt += 128) {
#pragma unroll
        for (int j = 0; j < 4; j++)
            gload_lds16(srcA + (long)j * 8 * Kd * 2 + kt, Ash + (w * 32 + j * 8) * 128);
#pragma unroll
        for (int j = 0; j < NI; j++)
            gload_lds16(srcB + (long)j * 8 * Kd * 2 + kt,
                        Bsh + (w * (BN / 4) + j * 8) * 128);
        __syncthreads();
#pragma unroll
        for (int kk = 0; kk < 2; kk++) {
            bf16x8 af[4], bfr[NI];
            const int sw = (lm & 7) << 4;
            const int co = (kk * 64 + lg * 16);
#pragma unroll
            for (int mi = 0; mi < 4; mi++)
                af[mi] = *(const bf16x8*)(Ash + (wr * 64 + mi * 16 + lm) * 128 + (co ^ sw));
#pragma unroll
            for (int ni = 0; ni < NI; ni++)
                bfr[ni] = *(const bf16x8*)(Bsh + (wc * (BN / 2) + ni * 16 + lm) * 128 + (co ^ sw));
#pragma unroll
            for (int mi = 0; mi < 4; mi++)
#pragma unroll
                for (int ni = 0; ni < NI; ni++)
                    acc[mi][ni] = __builtin_amdgcn_mfma_f32_16x16x32_bf16(
                        af[mi], bfr[ni], acc[mi][ni], 0, 0, 0);
        }
        __syncthreads();
    }

    if constexpr (EPI == 0) {
        const int which = n0 >> 10;
        float cqp[NI];
#pragma unroll
        for (int ni = 0; ni < NI; ni++)
            cqp[ni] = __cosf(qp[(wc * (BN / 2) + ni * 16 + lm) & 63]);

        if (which == 2) {
            // ---- V: per-wave LDS transpose -> coalesced Vt[d][s] stores ----
            char* T = (w < 2 ? Ash : Bsh) + (w & 1) * 8192;
#pragma unroll
            for (int mi = 0; mi < 4; mi++)
#pragma unroll
                for (int r = 0; r < 4; r++)
#pragma unroll
                    for (int ni = 0; ni < NI; ni++) {
                        int row = ni * 16 + lm;            // d (0..63)
                        int col = mi * 16 + lg * 4 + r;    // s-local (0..63)
                        float val = __cosf(acc[mi][ni][r]) * cqp[ni];
                        *(__hip_bfloat16*)(T + row * 128 +
                                           ((col * 2) ^ ((row & 7) << 4))) =
                            __float2bfloat16(val);
                    }
            const int h  = ((n0 & 1023) >> 6) + wc;
            const int bh = (m0 >> 11) * NH + h;
            const int sbase = (m0 & 2047) + wr * 64;
#pragma unroll
            for (int j = 0; j < 8; j++) {
                int c = j * 64 + l;
                int d = c >> 3;
                int sc = (c & 7) * 16;
                uint4 v = *(const uint4*)(T + d * 128 + (sc ^ ((d & 7) << 4)));
                *(uint4*)((char*)(Vt + ((long)bh * HD + d) * S_LEN + sbase) + sc) = v;
            }
        } else {
#pragma unroll
            for (int mi = 0; mi < 4; mi++) {
#pragma unroll
                for (int r = 0; r < 4; r++) {
                    int m = m0 + wr * 64 + mi * 16 + lg * 4 + r;
                    int b = m >> 11, s = m & 2047;
#pragma unroll
                    for (int ni = 0; ni < NI; ni++) {
                        int n = n0 + wc * (BN / 2) + ni * 16 + lm;
                        int d = n & 63;
                        int h = (n & 1023) >> 6;
                        int bh = b * NH + h;
                        float val = __cosf(acc[mi][ni][r]) * cqp[ni];
                        if (which == 0)  // 0.125*log2(e) folded for exp2 softmax
                            Q[((long)bh * S_LEN + s) * HD + d] =
                                __float2bfloat16(val * 0.180336880f);
                        else
                            Kp[((long)bh * S_LEN + s) * HD + d] = __float2bfloat16(val);
                    }
                }
            }
        }
    } else {
#pragma unroll
        for (int mi = 0; mi < 4; mi++)
#pragma unroll
            for (int r = 0; r < 4; r++) {
                int m = m0 + wr * 64 + mi * 16 + lg * 4 + r;
#pragma unroll
                for (int ni = 0; ni < NI; ni++) {
                    int n = n0 + wc * (BN / 2) + ni * 16 + lm;
                    C[(long)m * 1024 + n] = acc[mi][ni][r];
                }
            }
    }
}

// ---------------------------------------------------------------------------
// Kernel 2: MFMA flash attention — r13 kernel verbatim (measured 50us, the
// best of the attn family). QBLK=64, grid 1024, XCD swizzle, double-buffered
// K/V DMA (one barrier/tile), 4 waves split 2x2 over (q-half, key-half),
// 32x32x16 MFMA, in-register P (cvt_pk + permlane32_swap, r8-verified),
// -8*log2e folded into the QK accumulator init, 32KB LDS -> 4 blocks/CU.
// ---------------------------------------------------------------------------
__global__ __launch_bounds__(256, 4) void attn_mfma(
    const __hip_bfloat16* __restrict__ Q,
    const __hip_bfloat16* __restrict__ K,
    const __hip_bfloat16* __restrict__ Vt,  // [B,H,D,S]
    __hip_bfloat16* __restrict__ O)
{
    __shared__ __align__(16) char Ksh[2][64 * 128];  // 64 keys x 64 d (swz)
    __shared__ __align__(16) char Vsh[2][64 * 128];  // 64 d x 64 keys (swz)

    const int L  = blockIdx.x;               // 0..1023
    const int bh = (L & 7) + (L >> 8) * 8;   // XCD swizzle (r12-proven)
    const int q0 = ((L >> 3) & 31) * 64;
    const int b  = bh >> 4, h = bh & 15;
    const int t  = threadIdx.x;
    const int w  = t >> 6;                   // wave 0..3
    const int qi = w & 1;                    // q-half (32 rows)
    const int ki = w >> 1;                   // key-half (32 keys)
    const int l  = t & 63;
    const int lo5 = l & 31;
    const int hi  = l >> 5;

    // Q fragments (pre-scaled by 0.125*log2e): q = q0 + qi*32 + lo5
    const char* Qr =
        (const char*)(Q + ((long)bh * S_LEN + q0 + qi * 32 + lo5) * HD);
    bf16x8 qf[4];
#pragma unroll
    for (int ks = 0; ks < 4; ks++)
        qf[ks] = *(const bf16x8*)(Qr + ks * 32 + hi * 16);

    f32x16 oacc[2] = {};
    float lsum = 0.f;
    const float EXPB = 11.54156033f;  // 8 * log2(e)

    const char* Kgb = (const char*)(K + (long)bh * S_LEN * HD);
    const char* Vgb = (const char*)(Vt + (long)bh * HD * S_LEN);

    // DMA staging: lane l covers LDS row w*8+(l>>3) (+32 chunk2), 16B col
    // (l&7). Linear LDS dest; source byte pre-swizzled by ((row&7)<<4).
    const int swb = ((l & 7) * 16) ^ (((l >> 3) & 7) << 4);
    const int row0 = w * 8 + (l >> 3);
    const char* Ksrc  = Kgb + (long)row0 * 128 + swb;                  // +kt*128
    const char* Vsrc0 = Vgb + (long)row0 * (S_LEN * 2) + swb;          // +kt*2
    const char* Vsrc1 = Vgb + (long)(row0 + 32) * (S_LEN * 2) + swb;   // +kt*2

    // prologue: stage tile 0 into buffer 0
    gload_lds16(Ksrc, Ksh[0] + w * 1024);
    gload_lds16(Ksrc + 32 * 128, Ksh[0] + w * 1024 + 4096);
    gload_lds16(Vsrc0, Vsh[0] + w * 1024);
    gload_lds16(Vsrc1, Vsh[0] + w * 1024 + 4096);

    const int swr = (lo5 & 7) << 4;  // read swizzle (row&7 == lo5&7 here)
    int cur = 0;
    for (int kt = 0; kt < S_LEN; kt += 64) {
        __syncthreads();  // vmcnt(0) drained -> buf[cur] staged; alt reads done

        if (kt + 64 < S_LEN) {  // stage next tile into alternate buffer
            int nk = kt + 64;
            gload_lds16(Ksrc + (long)nk * 128, Ksh[cur ^ 1] + w * 1024);
            gload_lds16(Ksrc + (long)(nk + 32) * 128, Ksh[cur ^ 1] + w * 1024 + 4096);
            gload_lds16(Vsrc0 + (long)nk * 2, Vsh[cur ^ 1] + w * 1024);
            gload_lds16(Vsrc1 + (long)nk * 2, Vsh[cur ^ 1] + w * 1024 + 4096);
        }

        const char* Kc = Ksh[cur];
        const char* Vc = Vsh[cur];

        // ---- S^T - EXPB = K Q^T + (-EXPB): acc INIT carries the bias ----
        f32x16 s;
#pragma unroll
        for (int r = 0; r < 16; r++) s[r] = -EXPB;
        const char* Krow = Kc + (ki * 32 + lo5) * 128;
        __builtin_amdgcn_s_setprio(1);
#pragma unroll
        for (int ks = 0; ks < 4; ks++) {
            bf16x8 kf = *(const bf16x8*)(Krow + ((ks * 32 + hi * 16) ^ swr));
            s = __builtin_amdgcn_mfma_f32_32x32x16_bf16(kf, qf[ks], s, 0, 0, 0);
        }
        __builtin_amdgcn_s_setprio(0);
        // s[r] = S[key=ki*32+(r&3)+8*(r>>2)+4*hi][q=lo5] - EXPB

        // ---- softmax + in-register P->PA (cvt_pk + permlane, r8-verified) --
        float p[16];
#pragma unroll
        for (int r = 0; r < 16; r++) p[r] = __builtin_amdgcn_exp2f(s[r]);
#pragma unroll
        for (int r = 0; r < 16; r += 4)
            lsum += (p[r] + p[r + 1]) + (p[r + 2] + p[r + 3]);
        unsigned c0, c1, c2, c3, c4, c5, c6, c7;
        asm("v_cvt_pk_bf16_f32 %0, %1, %2" : "=v"(c0) : "v"(p[0]),  "v"(p[1]));
        asm("v_cvt_pk_bf16_f32 %0, %1, %2" : "=v"(c1) : "v"(p[2]),  "v"(p[3]));
        asm("v_cvt_pk_bf16_f32 %0, %1, %2" : "=v"(c2) : "v"(p[4]),  "v"(p[5]));
        asm("v_cvt_pk_bf16_f32 %0, %1, %2" : "=v"(c3) : "v"(p[6]),  "v"(p[7]));
        asm("v_cvt_pk_bf16_f32 %0, %1, %2" : "=v"(c4) : "v"(p[8]),  "v"(p[9]));
        asm("v_cvt_pk_bf16_f32 %0, %1, %2" : "=v"(c5) : "v"(p[10]), "v"(p[11]));
        asm("v_cvt_pk_bf16_f32 %0, %1, %2" : "=v"(c6) : "v"(p[12]), "v"(p[13]));
        asm("v_cvt_pk_bf16_f32 %0, %1, %2" : "=v"(c7) : "v"(p[14]), "v"(p[15]));
        asm("v_permlane32_swap_b32 %0, %1" : "+v"(c0), "+v"(c2));
        asm("v_permlane32_swap_b32 %0, %1" : "+v"(c1), "+v"(c3));
        asm("v_permlane32_swap_b32 %0, %1" : "+v"(c4), "+v"(c6));
        asm("v_permlane32_swap_b32 %0, %1" : "+v"(c5), "+v"(c7));
        u32x4 w0 = {c0, c1, c2, c3};
        u32x4 w1 = {c4, c5, c6, c7};
        bf16x8 pa0 = __builtin_bit_cast(bf16x8, w0);  // keys ki*32 + 0..15
        bf16x8 pa1 = __builtin_bit_cast(bf16x8, w1);  // keys ki*32 + 16..31

        // ---- O += P V over this wave's 32 keys ----
        __builtin_amdgcn_s_setprio(1);
#pragma unroll
        for (int db = 0; db < 2; db++) {
            const char* Vrow = Vc + (db * 32 + lo5) * 128;
            bf16x8 vf0 = *(const bf16x8*)(Vrow + ((ki * 64 + hi * 16) ^ swr));
            bf16x8 vf1 = *(const bf16x8*)(Vrow + ((ki * 64 + 32 + hi * 16) ^ swr));
            oacc[db] = __builtin_amdgcn_mfma_f32_32x32x16_bf16(pa0, vf0, oacc[db], 0, 0, 0);
            oacc[db] = __builtin_amdgcn_mfma_f32_32x32x16_bf16(pa1, vf1, oacc[db], 0, 0, 0);
        }
        __builtin_amdgcn_s_setprio(0);
        cur ^= 1;
    }

    // ---- combine key-halves: lane lo5 holds q=lo5 after hi-reduce ----
    lsum += __shfl_xor(lsum, 32, 64);
    __syncthreads();  // main-loop LDS reads done; reuse Ksh/Vsh
    float* Osh = (float*)Ksh;        // 2 qi regions x 32x64 floats = 16 KB
    float* Lsh = (float*)Vsh;        // 2 qi regions x 64 floats
    if (ki == 1) {
        float* dst = Osh + qi * 2048;
#pragma unroll
        for (int db = 0; db < 2; db++)
#pragma unroll
            for (int r = 0; r < 16; r++)
                dst[(db * 16 + r) * 64 + l] = oacc[db][r];  // lane-major: no conflicts
        Lsh[qi * 64 + l] = lsum;
    }
    __syncthreads();
    if (ki == 0) {
        const float* src = Osh + qi * 2048;
#pragma unroll
        for (int db = 0; db < 2; db++)
#pragma unroll
            for (int r = 0; r < 16; r++)
                oacc[db][r] += src[(db * 16 + r) * 64 + l];
        lsum += Lsh[qi * 64 + l];
        float inv = 1.f / lsum;  // valid for q = lo5
#pragma unroll
        for (int r = 0; r < 16; r++) {
            int qr = (r & 3) + 8 * (r >> 2) + 4 * hi;
            float invr = __shfl(inv, qr, 32);
            int qrow = q0 + qi * 32 + qr;
            long base = ((long)b * S_LEN + qrow) * EMB + h * HD;
            O[base + lo5]      = __float2bfloat16(oacc[0][r] * invr);
            O[base + 32 + lo5] = __float2bfloat16(oacc[1][r] * invr);
        }
    }
}

extern "C" void kernel_launch(void* const* d_in, const int* in_sizes, int n_in,
                              void* d_out, int out_size, void* d_ws, size_t ws_size,
                              hipStream_t stream) {
    const float* x     = (const float*)d_in[0];   // [2,2048,1024]
    const float* qkv_w = (const float*)d_in[1];   // [3072,1024]
    const float* out_w = (const float*)d_in[2];   // [1024,1024]
    const float* qp    = (const float*)d_in[3];   // [64]
    float* out = (float*)d_out;                   // [2,2048,1024] fp32

    const long NELEM = (long)2 * S_LEN * EMB;     // 4,194,304
    __hip_bfloat16* Q   = (__hip_bfloat16*)d_ws;  // [B,H,S,D] (x 0.125*log2e)
    __hip_bfloat16* K   = Q + NELEM;              // [B,H,S,D]
    __hip_bfloat16* Vt  = K + NELEM;              // [B,H,D,S]
    __hip_bfloat16* O   = Vt + NELEM;             // [B,S,E]
    __hip_bfloat16* xb  = O + NELEM;              // [4096][1024]
    __hip_bfloat16* wqb = xb + NELEM;             // [3072][1024]
    __hip_bfloat16* wob = wqb + (long)3072 * 1024;// [1024][1024]

    dim3 blk(256);
    cvt_all<<<dim3(8192), blk, 0, stream>>>(x, qkv_w, out_w, xb, wqb, wob);
    // EPI=0: BN=128, grid 24x32=768 (1-D, XCD-swizzled: CH=96)
    gemm_mfma<0, 128, 24, 96><<<dim3(768), blk, 0, stream>>>(
        xb, wqb, qp, Q, K, Vt, nullptr);
    attn_mfma<<<dim3(1024), blk, 0, stream>>>(Q, K, Vt, O);
    // EPI=1: BN=64, grid 16x32=512 (2 blocks/CU; CH=64)
    gemm_mfma<1, 64, 16, 64><<<dim3(512), blk, 0, stream>>>(
        O, wob, nullptr, nullptr, nullptr, nullptr, out);
}